// Round 2
// baseline (234.849 us; speedup 1.0000x reference)
//
#include <hip/hip_runtime.h>
#include <hip/hip_bf16.h>
#include <math.h>

// Problem constants
#define BATCH 8
#define SEQ   2048
#define CH    512
#define ROWS  (BATCH * SEQ)   // 16384
#define INVSQ 0.044194173824159216f  // 1/sqrt(512)

// GEMM tile config for read kernel: 128x128 block tile, K-step 64
#define BM 128
#define BK 32
#define TILE_ELEMS (BM * BK)   // 4096 bf16 = 8 KB (one sub-tile)
#define TP 68                  // transpose-tile pitch (2-way conflict = free)

typedef __attribute__((ext_vector_type(8))) __bf16 bf16x8;
typedef __attribute__((ext_vector_type(4))) float f32x4;

__device__ inline unsigned short f2bf(float f) {
    unsigned u = __builtin_bit_cast(unsigned, f);
    u += 0x7fffu + ((u >> 16) & 1u);   // round-to-nearest-even
    return (unsigned short)(u >> 16);
}
__device__ inline float bf2f(unsigned short s) {
    unsigned u = ((unsigned)s) << 16;
    return __builtin_bit_cast(float, u);
}

// Async-stage one 128x32 bf16 sub-tile (8 KB) from global (row stride `stride`
// elems) into LDS. Layout: row-major [128][32] unpadded. (Used by read.)
__device__ __forceinline__ void stage_tile(
    const unsigned short* __restrict__ gbase, size_t stride,
    unsigned short* lds, int wave, int lane)
{
#pragma unroll
    for (int j = 0; j < 2; ++j) {
        int chunk = wave * 2 + j;                  // 0..7, 16 rows each
        int row = chunk * 16 + (lane >> 2);
        const unsigned short* g = gbase + (size_t)row * stride + ((lane & 3) << 3);
        __builtin_amdgcn_global_load_lds(
            (const __attribute__((address_space(1))) unsigned int*)g,
            (__attribute__((address_space(3))) unsigned int*)(lds + (chunk << 9)),
            16, 0, 0);
    }
}

// Load a 64-row x 32-k fragment set (4x bf16x8) from a 128x32 sub-tile.
__device__ __forceinline__ void load_frags(
    const unsigned short* lds, int w0, int l16, int quad, bf16x8* f)
{
#pragma unroll
    for (int r = 0; r < 4; ++r)
        f[r] = *(const bf16x8*)(lds + (w0 + r * 16 + l16) * BK + quad * 8);
}

// ---------------------------------------------------------------------------
// fuse_x: x fp32 [16384,512] -> out[:, :, 0:512] (fp32) AND xb (bf16).
// Also zeroes Z (blocks 0..63).
// ---------------------------------------------------------------------------
__global__ __launch_bounds__(256) void fuse_x_kernel(
    const float* __restrict__ x, unsigned short* __restrict__ xb,
    float* __restrict__ out, float* __restrict__ Z)
{
    if (blockIdx.x < 64) Z[blockIdx.x * 256 + threadIdx.x] = 0.f;
    size_t base = ((size_t)blockIdx.x * 256 + threadIdx.x) * 8;
    size_t row = base >> 9, c = base & 511;
    float4 v0 = *(const float4*)(x + base);
    float4 v1 = *(const float4*)(x + base + 4);
    float* o = out + row * 1024 + c;
    *(float4*)o = v0;
    *(float4*)(o + 4) = v1;
    alignas(16) unsigned short t[8];
    t[0] = f2bf(v0.x); t[1] = f2bf(v0.y); t[2] = f2bf(v0.z); t[3] = f2bf(v0.w);
    t[4] = f2bf(v1.x); t[5] = f2bf(v1.y); t[6] = f2bf(v1.z); t[7] = f2bf(v1.w);
    *(uint4*)(xb + base) = *(const uint4*)t;
}

// ---------------------------------------------------------------------------
// transpose_w: W fp32 [512 k][512 n] -> Wt bf16 [3][512 n][512 k]
// ---------------------------------------------------------------------------
__global__ __launch_bounds__(256) void transpose_w_kernel(
    const float* __restrict__ Wq, const float* __restrict__ Wk,
    const float* __restrict__ Wv, unsigned short* __restrict__ Wt)
{
    __shared__ unsigned short T[64 * TP];
    const int k0 = blockIdx.x * 64, n0 = blockIdx.y * 64, w = blockIdx.z;
    const float* W = (w == 0) ? Wq : (w == 1) ? Wk : Wv;
    const int tid = threadIdx.x;
#pragma unroll
    for (int i = 0; i < 2; ++i) {
        int slot = tid + i * 256;
        int kr = slot >> 3, c8 = (slot & 7) << 3;
        float4 a = *(const float4*)(W + (size_t)(k0 + kr) * CH + n0 + c8);
        float4 b = *(const float4*)(W + (size_t)(k0 + kr) * CH + n0 + c8 + 4);
        T[(c8 + 0) * TP + kr] = f2bf(a.x); T[(c8 + 1) * TP + kr] = f2bf(a.y);
        T[(c8 + 2) * TP + kr] = f2bf(a.z); T[(c8 + 3) * TP + kr] = f2bf(a.w);
        T[(c8 + 4) * TP + kr] = f2bf(b.x); T[(c8 + 5) * TP + kr] = f2bf(b.y);
        T[(c8 + 6) * TP + kr] = f2bf(b.z); T[(c8 + 7) * TP + kr] = f2bf(b.w);
    }
    __syncthreads();
#pragma unroll
    for (int i = 0; i < 2; ++i) {
        int slot = tid + i * 256;
        int nr = slot >> 3, k8 = (slot & 7) << 3;
        uint2 lo = *(const uint2*)(T + nr * TP + k8);
        uint2 hi = *(const uint2*)(T + nr * TP + k8 + 4);
        uint4 u; u.x = lo.x; u.y = lo.y; u.z = hi.x; u.w = hi.y;
        *(uint4*)(Wt + ((size_t)w * CH + n0 + nr) * CH + k0 + k8) = u;
    }
}

// ---------------------------------------------------------------------------
// transpose_v: vb bf16 [b][s][v] -> Vt bf16 [b][v][s], scaled by 1/Z[b][s].
// ---------------------------------------------------------------------------
__global__ __launch_bounds__(256) void transpose_v_kernel(
    const unsigned short* __restrict__ vb, const float* __restrict__ Z,
    unsigned short* __restrict__ Vt)
{
    __shared__ unsigned short T[64 * TP];
    const int s0 = blockIdx.x * 64, v0 = blockIdx.y * 64, b = blockIdx.z;
    const int tid = threadIdx.x;
#pragma unroll
    for (int i = 0; i < 2; ++i) {
        int slot = tid + i * 256;
        int sr = slot >> 3, c8 = (slot & 7) << 3;
        float inv = 1.0f / Z[b * SEQ + s0 + sr];
        uint4 raw = *(const uint4*)(vb + ((size_t)b * SEQ + s0 + sr) * CH + v0 + c8);
        const unsigned short* p = (const unsigned short*)&raw;
#pragma unroll
        for (int j = 0; j < 8; ++j)
            T[(c8 + j) * TP + sr] = f2bf(bf2f(p[j]) * inv);
    }
    __syncthreads();
#pragma unroll
    for (int i = 0; i < 2; ++i) {
        int slot = tid + i * 256;
        int vr = slot >> 3, s8 = (slot & 7) << 3;
        uint2 lo = *(const uint2*)(T + vr * TP + s8);
        uint2 hi = *(const uint2*)(T + vr * TP + s8 + 4);
        uint4 u; u.x = lo.x; u.y = lo.y; u.z = hi.x; u.w = hi.y;
        *(uint4*)(Vt + ((size_t)b * CH + v0 + vr) * SEQ + s0 + s8) = u;
    }
}

// ---------------------------------------------------------------------------
// Shared 2-phase counted-vmcnt pipeline pieces (verified in qkv8):
// A slab 128x32, B slab 256x32, both k-major stride CH, 16 K-tiles, 8 waves.
// LDS 48 KB: A[2][128][32] | B[2][256][32], XOR-swizzled slots (both sides).
// ---------------------------------------------------------------------------
#define MFMA_ROW(r, af) \
    acc[r][0] = __builtin_amdgcn_mfma_f32_16x16x32_bf16(af, b0, acc[r][0], 0, 0, 0); \
    acc[r][1] = __builtin_amdgcn_mfma_f32_16x16x32_bf16(af, b1, acc[r][1], 0, 0, 0); \
    acc[r][2] = __builtin_amdgcn_mfma_f32_16x16x32_bf16(af, b2, acc[r][2], 0, 0, 0); \
    acc[r][3] = __builtin_amdgcn_mfma_f32_16x16x32_bf16(af, b3, acc[r][3], 0, 0, 0);

#define PIPELINE_LOOP                                                         \
    stageA(0); stageB(0); stageB(1);                                          \
    asm volatile("s_waitcnt vmcnt(2)" ::: "memory");                          \
    __builtin_amdgcn_s_barrier();                                             \
    __builtin_amdgcn_sched_barrier(0);                                        \
    _Pragma("unroll")                                                         \
    for (int U = 0; U < 16; ++U) {                                            \
        const unsigned short* Ab = lds + (U & 1) * 4096;                      \
        const unsigned short* Bb = lds + 8192 + (U & 1) * 8192;               \
        bf16x8 a0, a1, b0, b1, b2, b3;                                        \
        b0 = *(const bf16x8*)(Bb + (brow +  0) * 32 + rswz);                  \
        b1 = *(const bf16x8*)(Bb + (brow + 16) * 32 + rswz);                  \
        b2 = *(const bf16x8*)(Bb + (brow + 32) * 32 + rswz);                  \
        b3 = *(const bf16x8*)(Bb + (brow + 48) * 32 + rswz);                  \
        a0 = *(const bf16x8*)(Ab + (arow +  0) * 32 + rswz);                  \
        a1 = *(const bf16x8*)(Ab + (arow + 16) * 32 + rswz);                  \
        stageA(U + 1);                                                        \
        __builtin_amdgcn_s_barrier();                                         \
        asm volatile("s_waitcnt lgkmcnt(0)" ::: "memory");                    \
        __builtin_amdgcn_sched_barrier(0);                                    \
        __builtin_amdgcn_s_setprio(1);                                        \
        MFMA_ROW(0, a0);                                                      \
        MFMA_ROW(1, a1);                                                      \
        __builtin_amdgcn_s_setprio(0);                                        \
        __builtin_amdgcn_s_barrier();                                         \
        __builtin_amdgcn_sched_barrier(0);                                    \
        a0 = *(const bf16x8*)(Ab + (arow + 32) * 32 + rswz);                  \
        a1 = *(const bf16x8*)(Ab + (arow + 48) * 32 + rswz);                  \
        stageB(U + 2);                                                        \
        __builtin_amdgcn_s_barrier();                                         \
        asm volatile("s_waitcnt lgkmcnt(0)" ::: "memory");                    \
        __builtin_amdgcn_sched_barrier(0);                                    \
        __builtin_amdgcn_s_setprio(1);                                        \
        MFMA_ROW(2, a0);                                                      \
        MFMA_ROW(3, a1);                                                      \
        __builtin_amdgcn_s_setprio(0);                                        \
        if (U <= 13)      asm volatile("s_waitcnt vmcnt(2)" ::: "memory");    \
        else if (U == 14) asm volatile("s_waitcnt vmcnt(0)" ::: "memory");    \
        __builtin_amdgcn_s_barrier();                                         \
        __builtin_amdgcn_sched_barrier(0);                                    \
    }

// ---------------------------------------------------------------------------
// qkv fused GEMM, phase-interleaved counted-vmcnt pipeline (T2+T3+T4+T5).
// C[n(weight row), m(x row)]: A = Wt [1536][512] k-major, B = xb [16384][512].
// Block tile 256(x) x 128(w), BK=32, 16 K-tiles, 8 waves (2 over w, 4 over x).
// ---------------------------------------------------------------------------
__global__ __launch_bounds__(512, 2) void qkv8_kernel(
    const unsigned short* __restrict__ xb, const unsigned short* __restrict__ Wt,
    const float* __restrict__ bq, const float* __restrict__ bk,
    const float* __restrict__ bv, unsigned short* __restrict__ qkv)
{
    __shared__ unsigned short lds[24576];   // 48 KB
    const int tid = threadIdx.x;
    const int lane = tid & 63, wave = tid >> 6;
    const int waveA = wave >> 2;            // 0..1: weight strip (64 rows)
    const int waveB = wave & 3;             // 0..3: x strip (64 rows)
    const int quad = lane >> 4, l16 = lane & 15;

    // Bijective XCD swizzle: 768 = 8 XCDs x 96. XCD c owns x-tiles 8c..8c+7
    // (= batch c) with all 12 w-tiles -> x-tile staged once per XCD L2.
    int id = (int)blockIdx.x;
    id = (id & 7) * 96 + (id >> 3);
    const int xt = id / 12, wt = id - xt * 12;
    const int xrow0 = xt << 8, wrow0 = wt << 7;

    const unsigned short* __restrict__ Wg = Wt + (size_t)wrow0 * CH;
    const unsigned short* __restrict__ Xg = xb + (size_t)xrow0 * CH;

    // Staging geometry: per-thread source (pre-swizzled slot), linear LDS dest.
    const int srow = tid >> 2;                               // 0..127
    const int scol = (((tid & 3) ^ ((tid >> 3) & 3)) << 3);  // swizzled src col
    const size_t ga  = (size_t)srow * CH + scol;
    const size_t gb1 = (size_t)(srow + 128) * CH + scol;
    const int wdst = wave * 512;                             // ushort idx in slab
    const int rswz = ((quad ^ ((l16 >> 1) & 3)) << 3);       // read-side swizzle
    const int arow = waveA * 64 + l16;
    const int brow = waveB * 64 + l16;

    f32x4 acc[4][4] = {};

    auto stageA = [&](int V) {   // 128x32 weight slab, 1 load/thread
        if (V >= 16) return;
        const unsigned short* g = Wg + ga + V * 32;
        unsigned short* d = lds + (V & 1) * 4096 + wdst;
        __builtin_amdgcn_global_load_lds(
            (const __attribute__((address_space(1))) unsigned int*)g,
            (__attribute__((address_space(3))) unsigned int*)d, 16, 0, 0);
    };
    auto stageB = [&](int V) {   // 256x32 x slab, 2 loads/thread
        if (V >= 16) return;
        const unsigned short* g0 = Xg + ga + V * 32;
        const unsigned short* g1 = Xg + gb1 + V * 32;
        unsigned short* d = lds + 8192 + (V & 1) * 8192 + wdst;
        __builtin_amdgcn_global_load_lds(
            (const __attribute__((address_space(1))) unsigned int*)g0,
            (__attribute__((address_space(3))) unsigned int*)d, 16, 0, 0);
        __builtin_amdgcn_global_load_lds(
            (const __attribute__((address_space(1))) unsigned int*)g1,
            (__attribute__((address_space(3))) unsigned int*)(d + 4096), 16, 0, 0);
    };

    PIPELINE_LOOP

    const int which = wrow0 >> 9;   // uniform per block
    const float* bias = (which == 0) ? bq : (which == 1) ? bk : bv;
    const float scale = (which == 0) ? INVSQ : 1.0f;
    unsigned short* outw = qkv + (size_t)which * ROWS * CH;
    const int colblk = wrow0 & 511;
#pragma unroll
    for (int r = 0; r < 4; ++r) {
        int colb = colblk + waveA * 64 + r * 16 + quad * 4;
        float4 b4 = *(const float4*)(bias + colb);
#pragma unroll
        for (int c = 0; c < 4; ++c) {
            int m = xrow0 + waveB * 64 + c * 16 + l16;
            alignas(8) unsigned short pk[4];
            pk[0] = f2bf((acc[r][c][0] + b4.x) * scale);
            pk[1] = f2bf((acc[r][c][1] + b4.y) * scale);
            pk[2] = f2bf((acc[r][c][2] + b4.z) * scale);
            pk[3] = f2bf((acc[r][c][3] + b4.w) * scale);
            *(uint2*)(outw + (size_t)m * CH + colb) = *(const uint2*)pk;
        }
    }
}

// ---------------------------------------------------------------------------
// logits, pipelined: C[s][t] = k_s . q_t (q pre-scaled by INVSQ).
// A = K-tile [128 s][512 k], B = Q-tile [256 t][512 k]. Same pipeline as qkv8.
// Triangle over (st 128-wide, tt2 256-wide): live iff st <= 2*tt2+1 -> 72
// pairs x 8 batches = 576 blocks. b = blockIdx&7 pins batch b to XCD b
// (batch q+k = 4 MB = one XCD L2).
// E[t][s] = exp(C) if s<=t else 0, packed 4-wide in s. Z[s] via shuffle+atomic.
// Coverage: for t-tile tau (128-wide), s-tiles 0..(tau|1) written, superset of
// the 0..tau that read_kernel consumes; extras are exact zeros, never read.
// ---------------------------------------------------------------------------
__global__ __launch_bounds__(512, 2) void logits8_kernel(
    const unsigned short* __restrict__ qb, const unsigned short* __restrict__ kb,
    unsigned short* __restrict__ E, float* __restrict__ Z)
{
    __shared__ unsigned short lds[24576];   // 48 KB
    const int tid = threadIdx.x;
    const int lane = tid & 63, wave = tid >> 6;
    const int waveA = wave >> 2;            // 0..1: s strip (64 rows)
    const int waveB = wave & 3;             // 0..3: t strip (64 rows)
    const int quad = lane >> 4, l16 = lane & 15;

    const int b = (int)blockIdx.x & 7;
    const int i = (int)blockIdx.x >> 3;     // 0..71 triangle index
    int tt2 = (int)((sqrtf(4.f * (float)i + 1.f) - 1.f) * 0.5f);
    int st = i - tt2 * (tt2 + 1);
    while (st < 0)           { --tt2; st = i - tt2 * (tt2 + 1); }
    while (st > 2 * tt2 + 1) { ++tt2; st = i - tt2 * (tt2 + 1); }
    const int m0s = st << 7;    // s rows (A, from k), 128-wide
    const int n0t = tt2 << 8;   // t cols (B, from q), 256-wide

    const unsigned short* __restrict__ Wg = kb + ((size_t)b * SEQ + m0s) * CH;
    const unsigned short* __restrict__ Xg = qb + ((size_t)b * SEQ + n0t) * CH;

    const int srow = tid >> 2;
    const int scol = (((tid & 3) ^ ((tid >> 3) & 3)) << 3);
    const size_t ga  = (size_t)srow * CH + scol;
    const size_t gb1 = (size_t)(srow + 128) * CH + scol;
    const int wdst = wave * 512;
    const int rswz = ((quad ^ ((l16 >> 1) & 3)) << 3);
    const int arow = waveA * 64 + l16;
    const int brow = waveB * 64 + l16;

    f32x4 acc[4][4] = {};

    auto stageA = [&](int V) {   // 128x32 K slab
        if (V >= 16) return;
        const unsigned short* g = Wg + ga + V * 32;
        unsigned short* d = lds + (V & 1) * 4096 + wdst;
        __builtin_amdgcn_global_load_lds(
            (const __attribute__((address_space(1))) unsigned int*)g,
            (__attribute__((address_space(3))) unsigned int*)d, 16, 0, 0);
    };
    auto stageB = [&](int V) {   // 256x32 Q slab
        if (V >= 16) return;
        const unsigned short* g0 = Xg + ga + V * 32;
        const unsigned short* g1 = Xg + gb1 + V * 32;
        unsigned short* d = lds + 8192 + (V & 1) * 8192 + wdst;
        __builtin_amdgcn_global_load_lds(
            (const __attribute__((address_space(1))) unsigned int*)g0,
            (__attribute__((address_space(3))) unsigned int*)d, 16, 0, 0);
        __builtin_amdgcn_global_load_lds(
            (const __attribute__((address_space(1))) unsigned int*)g1,
            (__attribute__((address_space(3))) unsigned int*)(d + 4096), 16, 0, 0);
    };

    PIPELINE_LOOP

    // Epilogue: causal mask, exp, Z partial sums, bf16 E write.
#pragma unroll
    for (int r = 0; r < 4; ++r) {
        int sb = m0s + waveA * 64 + r * 16 + quad * 4;
        float ev[4][4];
#pragma unroll
        for (int c = 0; c < 4; ++c) {
            int t = n0t + waveB * 64 + c * 16 + l16;
#pragma unroll
            for (int reg = 0; reg < 4; ++reg)
                ev[c][reg] = (sb + reg <= t) ? __expf(acc[r][c][reg]) : 0.f;
        }
#pragma unroll
        for (int reg = 0; reg < 4; ++reg) {
            float z = ev[0][reg] + ev[1][reg] + ev[2][reg] + ev[3][reg];
            z += __shfl_xor(z, 1);
            z += __shfl_xor(z, 2);
            z += __shfl_xor(z, 4);
            z += __shfl_xor(z, 8);
            if (l16 == 0) atomicAdd(&Z[b * SEQ + sb + reg], z);
        }
#pragma unroll
        for (int c = 0; c < 4; ++c) {
            int t = n0t + waveB * 64 + c * 16 + l16;
            alignas(8) unsigned short pk[4];
            pk[0] = f2bf(ev[c][0]); pk[1] = f2bf(ev[c][1]);
            pk[2] = f2bf(ev[c][2]); pk[3] = f2bf(ev[c][3]);
            *(uint2*)(E + ((size_t)b * SEQ + t) * SEQ + sb) = *(const uint2*)pk;
        }
    }
}
#undef PIPELINE_LOOP
#undef MFMA_ROW

// ---------------------------------------------------------------------------
// read, swapped: C[v][t] = sum_s Vt[v][s] * E[t][s] (causal K-loop, BK=64).
// A = Vt [b][v][s], B = E [b][t][s]. fp32 packed float4 -> out[:, :, 512+v].
// 1D grid 512, tt balance-swizzled.
// ---------------------------------------------------------------------------
__global__ __launch_bounds__(256) void read_kernel(
    const unsigned short* __restrict__ E, const unsigned short* __restrict__ Vt,
    float* __restrict__ out)
{
    __shared__ unsigned short As[2 * TILE_ELEMS];
    __shared__ unsigned short Bs[2 * TILE_ELEMS];
    const int id = blockIdx.x;
    const int b = id & 7;
    const int rem = id >> 3;
    const int mv = rem & 3;                  // v tile (4)
    const int r0 = rem >> 2;                 // 0..15
    const int tt = (r0 < 8) ? r0 : 23 - r0;  // pairs (r0, r0+8) -> tt sums to 15
    const int m0v = mv * BM;
    const int n0t = tt * BM;
    const int Kmax = (tt + 1) * BM;
    const int tid = threadIdx.x;
    const int lane = tid & 63, wave = tid >> 6;
    const int wm = (wave >> 1) * 64, wn = (wave & 1) * 64;
    const int quad = lane >> 4, l16 = lane & 15;
    const unsigned short* Vb = Vt + (size_t)b * CH * SEQ;   // [v][s]
    const unsigned short* Eb = E + (size_t)b * SEQ * SEQ;   // [t][s]

    f32x4 acc[4][4] = {};
    for (int kk = 0; kk < Kmax; kk += 64) {
        stage_tile(Vb + (size_t)m0v * SEQ + kk,      SEQ, As,              wave, lane);
        stage_tile(Vb + (size_t)m0v * SEQ + kk + 32, SEQ, As + TILE_ELEMS, wave, lane);
        stage_tile(Eb + (size_t)n0t * SEQ + kk,      SEQ, Bs,              wave, lane);
        stage_tile(Eb + (size_t)n0t * SEQ + kk + 32, SEQ, Bs + TILE_ELEMS, wave, lane);
        __syncthreads();
#pragma unroll
        for (int h = 0; h < 2; ++h) {
            bf16x8 a[4], bb[4];
            load_frags(As + h * TILE_ELEMS, wm, l16, quad, a);
            load_frags(Bs + h * TILE_ELEMS, wn, l16, quad, bb);
#pragma unroll
            for (int r = 0; r < 4; ++r)
#pragma unroll
                for (int c = 0; c < 4; ++c)
                    acc[r][c] = __builtin_amdgcn_mfma_f32_16x16x32_bf16(a[r], bb[c], acc[r][c], 0, 0, 0);
        }
        __syncthreads();
    }
#pragma unroll
    for (int r = 0; r < 4; ++r) {
        int v = 512 + m0v + wm + r * 16 + quad * 4;
#pragma unroll
        for (int c = 0; c < 4; ++c) {
            int t = n0t + wn + c * 16 + l16;
            float4 f;
            f.x = acc[r][c][0]; f.y = acc[r][c][1];
            f.z = acc[r][c][2]; f.w = acc[r][c][3];
            *(float4*)(out + ((size_t)b * SEQ + t) * 1024 + v) = f;
        }
    }
}

extern "C" void kernel_launch(void* const* d_in, const int* in_sizes, int n_in,
                              void* d_out, int out_size, void* d_ws, size_t ws_size,
                              hipStream_t stream) {
    const float* x  = (const float*)d_in[0];
    const float* Wq = (const float*)d_in[1];
    const float* bq = (const float*)d_in[2];
    const float* Wk = (const float*)d_in[3];
    const float* bk = (const float*)d_in[4];
    const float* Wv = (const float*)d_in[5];
    const float* bv = (const float*)d_in[6];
    float* out = (float*)d_out;

    char* ws = (char*)d_ws;
    const size_t QKV_BYTES = (size_t)ROWS * CH * 2;              // 16,777,216
    const size_t E_BYTES   = (size_t)BATCH * SEQ * SEQ * 2;      // 67,108,864
    unsigned short* qkv = (unsigned short*)ws;                   // q,k,v contiguous
    unsigned short* qb = qkv;
    unsigned short* kb = (unsigned short*)(ws + QKV_BYTES);
    unsigned short* vb = (unsigned short*)(ws + 2 * QKV_BYTES);
    unsigned short* E  = (unsigned short*)(ws + 3 * QKV_BYTES);
    float* Z = (float*)(ws + 3 * QKV_BYTES + E_BYTES);
    // Aliases (lifetimes disjoint on the in-order stream):
    unsigned short* xb = E;                                       // dead before logits writes E
    unsigned short* Wt = (unsigned short*)((char*)E + QKV_BYTES); // dead before logits writes E
    unsigned short* Vt = qb;                                      // qb dead after logits

    dim3 blk(256);
    fuse_x_kernel<<<dim3(4096), blk, 0, stream>>>(x, xb, out, Z);
    transpose_w_kernel<<<dim3(8, 8, 3), blk, 0, stream>>>(Wq, Wk, Wv, Wt);
    qkv8_kernel<<<dim3(768), dim3(512), 0, stream>>>(xb, Wt, bq, bk, bv, qkv);
    logits8_kernel<<<dim3(576), dim3(512), 0, stream>>>(qb, kb, E, Z);
    transpose_v_kernel<<<dim3(32, 8, 8), blk, 0, stream>>>(vb, Z, Vt);
    read_kernel<<<dim3(512), blk, 0, stream>>>(E, Vt, out);
}

// Round 3
// 224.659 us; speedup vs baseline: 1.0454x; 1.0454x over previous
//
#include <hip/hip_runtime.h>
#include <hip/hip_bf16.h>
#include <math.h>

// Problem constants
#define BATCH 8
#define SEQ   2048
#define CH    512
#define ROWS  (BATCH * SEQ)   // 16384
#define INVSQ 0.044194173824159216f  // 1/sqrt(512)

#define BM 128
#define TP 68                  // transpose-tile pitch (2-way conflict = free)

typedef __attribute__((ext_vector_type(8))) __bf16 bf16x8;
typedef __attribute__((ext_vector_type(4))) float f32x4;

__device__ inline unsigned short f2bf(float f) {
    unsigned u = __builtin_bit_cast(unsigned, f);
    u += 0x7fffu + ((u >> 16) & 1u);   // round-to-nearest-even
    return (unsigned short)(u >> 16);
}
__device__ inline float bf2f(unsigned short s) {
    unsigned u = ((unsigned)s) << 16;
    return __builtin_bit_cast(float, u);
}

// ---------------------------------------------------------------------------
// fuse_x: x fp32 [16384,512] -> out[:, :, 0:512] (fp32) AND xb (bf16).
// Also zeroes Z (blocks 0..63).
// ---------------------------------------------------------------------------
__global__ __launch_bounds__(256) void fuse_x_kernel(
    const float* __restrict__ x, unsigned short* __restrict__ xb,
    float* __restrict__ out, float* __restrict__ Z)
{
    if (blockIdx.x < 64) Z[blockIdx.x * 256 + threadIdx.x] = 0.f;
    size_t base = ((size_t)blockIdx.x * 256 + threadIdx.x) * 8;
    size_t row = base >> 9, c = base & 511;
    float4 v0 = *(const float4*)(x + base);
    float4 v1 = *(const float4*)(x + base + 4);
    float* o = out + row * 1024 + c;
    *(float4*)o = v0;
    *(float4*)(o + 4) = v1;
    alignas(16) unsigned short t[8];
    t[0] = f2bf(v0.x); t[1] = f2bf(v0.y); t[2] = f2bf(v0.z); t[3] = f2bf(v0.w);
    t[4] = f2bf(v1.x); t[5] = f2bf(v1.y); t[6] = f2bf(v1.z); t[7] = f2bf(v1.w);
    *(uint4*)(xb + base) = *(const uint4*)t;
}

// ---------------------------------------------------------------------------
// transpose_w: W fp32 [512 k][512 n] -> Wt bf16 [3][512 n][512 k]
// ---------------------------------------------------------------------------
__global__ __launch_bounds__(256) void transpose_w_kernel(
    const float* __restrict__ Wq, const float* __restrict__ Wk,
    const float* __restrict__ Wv, unsigned short* __restrict__ Wt)
{
    __shared__ unsigned short T[64 * TP];
    const int k0 = blockIdx.x * 64, n0 = blockIdx.y * 64, w = blockIdx.z;
    const float* W = (w == 0) ? Wq : (w == 1) ? Wk : Wv;
    const int tid = threadIdx.x;
#pragma unroll
    for (int i = 0; i < 2; ++i) {
        int slot = tid + i * 256;
        int kr = slot >> 3, c8 = (slot & 7) << 3;
        float4 a = *(const float4*)(W + (size_t)(k0 + kr) * CH + n0 + c8);
        float4 b = *(const float4*)(W + (size_t)(k0 + kr) * CH + n0 + c8 + 4);
        T[(c8 + 0) * TP + kr] = f2bf(a.x); T[(c8 + 1) * TP + kr] = f2bf(a.y);
        T[(c8 + 2) * TP + kr] = f2bf(a.z); T[(c8 + 3) * TP + kr] = f2bf(a.w);
        T[(c8 + 4) * TP + kr] = f2bf(b.x); T[(c8 + 5) * TP + kr] = f2bf(b.y);
        T[(c8 + 6) * TP + kr] = f2bf(b.z); T[(c8 + 7) * TP + kr] = f2bf(b.w);
    }
    __syncthreads();
#pragma unroll
    for (int i = 0; i < 2; ++i) {
        int slot = tid + i * 256;
        int nr = slot >> 3, k8 = (slot & 7) << 3;
        uint2 lo = *(const uint2*)(T + nr * TP + k8);
        uint2 hi = *(const uint2*)(T + nr * TP + k8 + 4);
        uint4 u; u.x = lo.x; u.y = lo.y; u.z = hi.x; u.w = hi.y;
        *(uint4*)(Wt + ((size_t)w * CH + n0 + nr) * CH + k0 + k8) = u;
    }
}

// ---------------------------------------------------------------------------
// transpose_v: vb bf16 [b][s][v] -> Vt bf16 [b][v][s], scaled by 1/Z[b][s].
// ---------------------------------------------------------------------------
__global__ __launch_bounds__(256) void transpose_v_kernel(
    const unsigned short* __restrict__ vb, const float* __restrict__ Z,
    unsigned short* __restrict__ Vt)
{
    __shared__ unsigned short T[64 * TP];
    const int s0 = blockIdx.x * 64, v0 = blockIdx.y * 64, b = blockIdx.z;
    const int tid = threadIdx.x;
#pragma unroll
    for (int i = 0; i < 2; ++i) {
        int slot = tid + i * 256;
        int sr = slot >> 3, c8 = (slot & 7) << 3;
        float inv = 1.0f / Z[b * SEQ + s0 + sr];
        uint4 raw = *(const uint4*)(vb + ((size_t)b * SEQ + s0 + sr) * CH + v0 + c8);
        const unsigned short* p = (const unsigned short*)&raw;
#pragma unroll
        for (int j = 0; j < 8; ++j)
            T[(c8 + j) * TP + sr] = f2bf(bf2f(p[j]) * inv);
    }
    __syncthreads();
#pragma unroll
    for (int i = 0; i < 2; ++i) {
        int slot = tid + i * 256;
        int vr = slot >> 3, s8 = (slot & 7) << 3;
        uint2 lo = *(const uint2*)(T + vr * TP + s8);
        uint2 hi = *(const uint2*)(T + vr * TP + s8 + 4);
        uint4 u; u.x = lo.x; u.y = lo.y; u.z = hi.x; u.w = hi.y;
        *(uint4*)(Vt + ((size_t)b * CH + v0 + vr) * SEQ + s0 + s8) = u;
    }
}

// ---------------------------------------------------------------------------
// Shared 2-phase counted-vmcnt pipeline pieces (verified in qkv8/logits8):
// 512-thread variant: A slab 128x32, B slab 256x32, k-major stride CH,
// 16 K-tiles, 8 waves. LDS 48 KB, XOR-swizzled slots (both sides).
// ---------------------------------------------------------------------------
#define MFMA_ROW(r, af) \
    acc[r][0] = __builtin_amdgcn_mfma_f32_16x16x32_bf16(af, b0, acc[r][0], 0, 0, 0); \
    acc[r][1] = __builtin_amdgcn_mfma_f32_16x16x32_bf16(af, b1, acc[r][1], 0, 0, 0); \
    acc[r][2] = __builtin_amdgcn_mfma_f32_16x16x32_bf16(af, b2, acc[r][2], 0, 0, 0); \
    acc[r][3] = __builtin_amdgcn_mfma_f32_16x16x32_bf16(af, b3, acc[r][3], 0, 0, 0);

#define PIPELINE_LOOP                                                         \
    stageA(0); stageB(0); stageB(1);                                          \
    asm volatile("s_waitcnt vmcnt(2)" ::: "memory");                          \
    __builtin_amdgcn_s_barrier();                                             \
    __builtin_amdgcn_sched_barrier(0);                                        \
    _Pragma("unroll")                                                         \
    for (int U = 0; U < 16; ++U) {                                            \
        const unsigned short* Ab = lds + (U & 1) * 4096;                      \
        const unsigned short* Bb = lds + 8192 + (U & 1) * 8192;               \
        bf16x8 a0, a1, b0, b1, b2, b3;                                        \
        b0 = *(const bf16x8*)(Bb + (brow +  0) * 32 + rswz);                  \
        b1 = *(const bf16x8*)(Bb + (brow + 16) * 32 + rswz);                  \
        b2 = *(const bf16x8*)(Bb + (brow + 32) * 32 + rswz);                  \
        b3 = *(const bf16x8*)(Bb + (brow + 48) * 32 + rswz);                  \
        a0 = *(const bf16x8*)(Ab + (arow +  0) * 32 + rswz);                  \
        a1 = *(const bf16x8*)(Ab + (arow + 16) * 32 + rswz);                  \
        stageA(U + 1);                                                        \
        __builtin_amdgcn_s_barrier();                                         \
        asm volatile("s_waitcnt lgkmcnt(0)" ::: "memory");                    \
        __builtin_amdgcn_sched_barrier(0);                                    \
        __builtin_amdgcn_s_setprio(1);                                        \
        MFMA_ROW(0, a0);                                                      \
        MFMA_ROW(1, a1);                                                      \
        __builtin_amdgcn_s_setprio(0);                                        \
        __builtin_amdgcn_s_barrier();                                         \
        __builtin_amdgcn_sched_barrier(0);                                    \
        a0 = *(const bf16x8*)(Ab + (arow + 32) * 32 + rswz);                  \
        a1 = *(const bf16x8*)(Ab + (arow + 48) * 32 + rswz);                  \
        stageB(U + 2);                                                        \
        __builtin_amdgcn_s_barrier();                                         \
        asm volatile("s_waitcnt lgkmcnt(0)" ::: "memory");                    \
        __builtin_amdgcn_sched_barrier(0);                                    \
        __builtin_amdgcn_s_setprio(1);                                        \
        MFMA_ROW(2, a0);                                                      \
        MFMA_ROW(3, a1);                                                      \
        __builtin_amdgcn_s_setprio(0);                                        \
        if (U <= 13)      asm volatile("s_waitcnt vmcnt(2)" ::: "memory");    \
        else if (U == 14) asm volatile("s_waitcnt vmcnt(0)" ::: "memory");    \
        __builtin_amdgcn_s_barrier();                                         \
        __builtin_amdgcn_sched_barrier(0);                                    \
    }

// ---------------------------------------------------------------------------
// qkv fused GEMM, phase-interleaved counted-vmcnt pipeline (T2+T3+T4+T5).
// C[n(weight row), m(x row)]: A = Wt [1536][512] k-major, B = xb [16384][512].
// Block tile 256(x) x 128(w), BK=32, 16 K-tiles, 8 waves (2 over w, 4 over x).
// ---------------------------------------------------------------------------
__global__ __launch_bounds__(512, 2) void qkv8_kernel(
    const unsigned short* __restrict__ xb, const unsigned short* __restrict__ Wt,
    const float* __restrict__ bq, const float* __restrict__ bk,
    const float* __restrict__ bv, unsigned short* __restrict__ qkv)
{
    __shared__ unsigned short lds[24576];   // 48 KB
    const int tid = threadIdx.x;
    const int lane = tid & 63, wave = tid >> 6;
    const int waveA = wave >> 2;            // 0..1: weight strip (64 rows)
    const int waveB = wave & 3;             // 0..3: x strip (64 rows)
    const int quad = lane >> 4, l16 = lane & 15;

    // Bijective XCD swizzle: 768 = 8 XCDs x 96. XCD c owns x-tiles 8c..8c+7
    // (= batch c) with all 12 w-tiles -> x-tile staged once per XCD L2.
    int id = (int)blockIdx.x;
    id = (id & 7) * 96 + (id >> 3);
    const int xt = id / 12, wt = id - xt * 12;
    const int xrow0 = xt << 8, wrow0 = wt << 7;

    const unsigned short* __restrict__ Wg = Wt + (size_t)wrow0 * CH;
    const unsigned short* __restrict__ Xg = xb + (size_t)xrow0 * CH;

    // Staging geometry: per-thread source (pre-swizzled slot), linear LDS dest.
    const int srow = tid >> 2;                               // 0..127
    const int scol = (((tid & 3) ^ ((tid >> 3) & 3)) << 3);  // swizzled src col
    const size_t ga  = (size_t)srow * CH + scol;
    const size_t gb1 = (size_t)(srow + 128) * CH + scol;
    const int wdst = wave * 512;                             // ushort idx in slab
    const int rswz = ((quad ^ ((l16 >> 1) & 3)) << 3);       // read-side swizzle
    const int arow = waveA * 64 + l16;
    const int brow = waveB * 64 + l16;

    f32x4 acc[4][4] = {};

    auto stageA = [&](int V) {   // 128x32 weight slab, 1 load/thread
        if (V >= 16) return;
        const unsigned short* g = Wg + ga + V * 32;
        unsigned short* d = lds + (V & 1) * 4096 + wdst;
        __builtin_amdgcn_global_load_lds(
            (const __attribute__((address_space(1))) unsigned int*)g,
            (__attribute__((address_space(3))) unsigned int*)d, 16, 0, 0);
    };
    auto stageB = [&](int V) {   // 256x32 x slab, 2 loads/thread
        if (V >= 16) return;
        const unsigned short* g0 = Xg + ga + V * 32;
        const unsigned short* g1 = Xg + gb1 + V * 32;
        unsigned short* d = lds + 8192 + (V & 1) * 8192 + wdst;
        __builtin_amdgcn_global_load_lds(
            (const __attribute__((address_space(1))) unsigned int*)g0,
            (__attribute__((address_space(3))) unsigned int*)d, 16, 0, 0);
        __builtin_amdgcn_global_load_lds(
            (const __attribute__((address_space(1))) unsigned int*)g1,
            (__attribute__((address_space(3))) unsigned int*)(d + 4096), 16, 0, 0);
    };

    PIPELINE_LOOP

    const int which = wrow0 >> 9;   // uniform per block
    const float* bias = (which == 0) ? bq : (which == 1) ? bk : bv;
    const float scale = (which == 0) ? INVSQ : 1.0f;
    unsigned short* outw = qkv + (size_t)which * ROWS * CH;
    const int colblk = wrow0 & 511;
#pragma unroll
    for (int r = 0; r < 4; ++r) {
        int colb = colblk + waveA * 64 + r * 16 + quad * 4;
        float4 b4 = *(const float4*)(bias + colb);
#pragma unroll
        for (int c = 0; c < 4; ++c) {
            int m = xrow0 + waveB * 64 + c * 16 + l16;
            alignas(8) unsigned short pk[4];
            pk[0] = f2bf((acc[r][c][0] + b4.x) * scale);
            pk[1] = f2bf((acc[r][c][1] + b4.y) * scale);
            pk[2] = f2bf((acc[r][c][2] + b4.z) * scale);
            pk[3] = f2bf((acc[r][c][3] + b4.w) * scale);
            *(uint2*)(outw + (size_t)m * CH + colb) = *(const uint2*)pk;
        }
    }
}

// ---------------------------------------------------------------------------
// logits, pipelined: C[s][t] = k_s . q_t (q pre-scaled by INVSQ).
// A = K-tile [128 s][512 k], B = Q-tile [256 t][512 k]. Same pipeline as qkv8.
// Triangle over (st 128-wide, tt2 256-wide): live iff st <= 2*tt2+1 -> 72
// pairs x 8 batches = 576 blocks. b = blockIdx&7 pins batch b to XCD b.
// E[t][s] = exp(C) if s<=t else 0. Z[s] via shuffle+atomic.
// Coverage: for t-tile tau (128-wide), s-tiles 0..(tau|1) written, superset of
// the 0..tau that read consumes; extras are exact zeros, never read.
// ---------------------------------------------------------------------------
__global__ __launch_bounds__(512, 2) void logits8_kernel(
    const unsigned short* __restrict__ qb, const unsigned short* __restrict__ kb,
    unsigned short* __restrict__ E, float* __restrict__ Z)
{
    __shared__ unsigned short lds[24576];   // 48 KB
    const int tid = threadIdx.x;
    const int lane = tid & 63, wave = tid >> 6;
    const int waveA = wave >> 2;            // 0..1: s strip (64 rows)
    const int waveB = wave & 3;             // 0..3: t strip (64 rows)
    const int quad = lane >> 4, l16 = lane & 15;

    const int b = (int)blockIdx.x & 7;
    const int i = (int)blockIdx.x >> 3;     // 0..71 triangle index
    int tt2 = (int)((sqrtf(4.f * (float)i + 1.f) - 1.f) * 0.5f);
    int st = i - tt2 * (tt2 + 1);
    while (st < 0)           { --tt2; st = i - tt2 * (tt2 + 1); }
    while (st > 2 * tt2 + 1) { ++tt2; st = i - tt2 * (tt2 + 1); }
    const int m0s = st << 7;    // s rows (A, from k), 128-wide
    const int n0t = tt2 << 8;   // t cols (B, from q), 256-wide

    const unsigned short* __restrict__ Wg = kb + ((size_t)b * SEQ + m0s) * CH;
    const unsigned short* __restrict__ Xg = qb + ((size_t)b * SEQ + n0t) * CH;

    const int srow = tid >> 2;
    const int scol = (((tid & 3) ^ ((tid >> 3) & 3)) << 3);
    const size_t ga  = (size_t)srow * CH + scol;
    const size_t gb1 = (size_t)(srow + 128) * CH + scol;
    const int wdst = wave * 512;
    const int rswz = ((quad ^ ((l16 >> 1) & 3)) << 3);
    const int arow = waveA * 64 + l16;
    const int brow = waveB * 64 + l16;

    f32x4 acc[4][4] = {};

    auto stageA = [&](int V) {   // 128x32 K slab
        if (V >= 16) return;
        const unsigned short* g = Wg + ga + V * 32;
        unsigned short* d = lds + (V & 1) * 4096 + wdst;
        __builtin_amdgcn_global_load_lds(
            (const __attribute__((address_space(1))) unsigned int*)g,
            (__attribute__((address_space(3))) unsigned int*)d, 16, 0, 0);
    };
    auto stageB = [&](int V) {   // 256x32 Q slab
        if (V >= 16) return;
        const unsigned short* g0 = Xg + ga + V * 32;
        const unsigned short* g1 = Xg + gb1 + V * 32;
        unsigned short* d = lds + 8192 + (V & 1) * 8192 + wdst;
        __builtin_amdgcn_global_load_lds(
            (const __attribute__((address_space(1))) unsigned int*)g0,
            (__attribute__((address_space(3))) unsigned int*)d, 16, 0, 0);
        __builtin_amdgcn_global_load_lds(
            (const __attribute__((address_space(1))) unsigned int*)g1,
            (__attribute__((address_space(3))) unsigned int*)(d + 4096), 16, 0, 0);
    };

    PIPELINE_LOOP

    // Epilogue: causal mask, exp, Z partial sums, bf16 E write.
#pragma unroll
    for (int r = 0; r < 4; ++r) {
        int sb = m0s + waveA * 64 + r * 16 + quad * 4;
        float ev[4][4];
#pragma unroll
        for (int c = 0; c < 4; ++c) {
            int t = n0t + waveB * 64 + c * 16 + l16;
#pragma unroll
            for (int reg = 0; reg < 4; ++reg)
                ev[c][reg] = (sb + reg <= t) ? __expf(acc[r][c][reg]) : 0.f;
        }
#pragma unroll
        for (int reg = 0; reg < 4; ++reg) {
            float z = ev[0][reg] + ev[1][reg] + ev[2][reg] + ev[3][reg];
            z += __shfl_xor(z, 1);
            z += __shfl_xor(z, 2);
            z += __shfl_xor(z, 4);
            z += __shfl_xor(z, 8);
            if (l16 == 0) atomicAdd(&Z[b * SEQ + sb + reg], z);
        }
#pragma unroll
        for (int c = 0; c < 4; ++c) {
            int t = n0t + waveB * 64 + c * 16 + l16;
            alignas(8) unsigned short pk[4];
            pk[0] = f2bf(ev[c][0]); pk[1] = f2bf(ev[c][1]);
            pk[2] = f2bf(ev[c][2]); pk[3] = f2bf(ev[c][3]);
            *(uint2*)(E + ((size_t)b * SEQ + t) * SEQ + sb) = *(const uint2*)pk;
        }
    }
}
#undef PIPELINE_LOOP

// ---------------------------------------------------------------------------
// read, pipelined 256-thread variant: C[v][t] = sum_s Vt[v][s] * E[t][s].
// A = Vt tile [128 v][s], B = E tile [128 t][s], both stride SEQ. BK=32,
// runtime NT = 4*(tt+1) K-tiles (causal). 4 waves (2 over v, 2 over t),
// per-wave 64x64 acc[4][4]. LDS 32 KB: A[2][128][32] | B[2][128][32],
// XOR-swizzled slots both sides. Staging: 2 loads/thread per slab ->
// steady-state vmcnt(2) (only newest B pair in flight), drain at NT-2.
// Grid 512 (4v x 16tt-balance-swizzled x 8b), b = blockIdx&7 pins XCD.
// ---------------------------------------------------------------------------
__global__ __launch_bounds__(256, 2) void read8_kernel(
    const unsigned short* __restrict__ E, const unsigned short* __restrict__ Vt,
    float* __restrict__ out)
{
    __shared__ unsigned short lds[16384];   // 32 KB
    const int tid = threadIdx.x;
    const int lane = tid & 63, wave = tid >> 6;
    const int waveA = wave >> 1;            // 0..1: v strip (64 rows)
    const int waveB = wave & 1;             // 0..1: t strip (64 rows)
    const int quad = lane >> 4, l16 = lane & 15;

    const int id = blockIdx.x;
    const int b = id & 7;
    const int rem = id >> 3;
    const int mv = rem & 3;                  // v tile (4)
    const int r0 = rem >> 2;                 // 0..15
    const int tt = (r0 < 8) ? r0 : 23 - r0;  // paired so per-CU work balances
    const int m0v = mv * BM;
    const int n0t = tt * BM;
    const int NT = (tt + 1) * 4;             // K-tiles of 32 (causal extent)

    const unsigned short* __restrict__ Ag = Vt + ((size_t)b * CH + m0v) * SEQ;
    const unsigned short* __restrict__ Bg = E + ((size_t)b * SEQ + n0t) * SEQ;

    // Staging: lane-linear LDS dest; source col slot pre-swizzled.
    const int scol = (((lane & 3) ^ ((lane >> 3) & 3)) << 3);
    const int srow = wave * 16 + (lane >> 2);       // 0..63 within half-slab
    const size_t ga0 = (size_t)srow * SEQ + scol;
    const size_t ga1 = (size_t)(srow + 64) * SEQ + scol;
    const int wdst = wave * 512;
    const int rswz = ((quad ^ ((l16 >> 1) & 3)) << 3);
    const int arow = waveA * 64 + l16;
    const int brow = waveB * 64 + l16;

    f32x4 acc[4][4] = {};

    auto stageA = [&](int V) {   // 128x32 Vt slab, 2 loads/thread
        if (V >= NT) return;
        const unsigned short* g0 = Ag + ga0 + V * 32;
        const unsigned short* g1 = Ag + ga1 + V * 32;
        unsigned short* d = lds + (V & 1) * 4096 + wdst;
        __builtin_amdgcn_global_load_lds(
            (const __attribute__((address_space(1))) unsigned int*)g0,
            (__attribute__((address_space(3))) unsigned int*)d, 16, 0, 0);
        __builtin_amdgcn_global_load_lds(
            (const __attribute__((address_space(1))) unsigned int*)g1,
            (__attribute__((address_space(3))) unsigned int*)(d + 2048), 16, 0, 0);
    };
    auto stageB = [&](int V) {   // 128x32 E slab, 2 loads/thread
        if (V >= NT) return;
        const unsigned short* g0 = Bg + ga0 + V * 32;
        const unsigned short* g1 = Bg + ga1 + V * 32;
        unsigned short* d = lds + 8192 + (V & 1) * 4096 + wdst;
        __builtin_amdgcn_global_load_lds(
            (const __attribute__((address_space(1))) unsigned int*)g0,
            (__attribute__((address_space(3))) unsigned int*)d, 16, 0, 0);
        __builtin_amdgcn_global_load_lds(
            (const __attribute__((address_space(1))) unsigned int*)g1,
            (__attribute__((address_space(3))) unsigned int*)(d + 2048), 16, 0, 0);
    };

    stageA(0); stageB(0); stageB(1);
    asm volatile("s_waitcnt vmcnt(2)" ::: "memory");
    __builtin_amdgcn_s_barrier();
    __builtin_amdgcn_sched_barrier(0);

#pragma unroll 2
    for (int U = 0; U < NT; ++U) {
        const unsigned short* Ab = lds + (U & 1) * 4096;
        const unsigned short* Bb = lds + 8192 + (U & 1) * 4096;
        bf16x8 a0, a1, b0, b1, b2, b3;
        // ---- phase 1 ----
        b0 = *(const bf16x8*)(Bb + (brow +  0) * 32 + rswz);
        b1 = *(const bf16x8*)(Bb + (brow + 16) * 32 + rswz);
        b2 = *(const bf16x8*)(Bb + (brow + 32) * 32 + rswz);
        b3 = *(const bf16x8*)(Bb + (brow + 48) * 32 + rswz);
        a0 = *(const bf16x8*)(Ab + (arow +  0) * 32 + rswz);
        a1 = *(const bf16x8*)(Ab + (arow + 16) * 32 + rswz);
        stageA(U + 1);
        __builtin_amdgcn_s_barrier();
        asm volatile("s_waitcnt lgkmcnt(0)" ::: "memory");
        __builtin_amdgcn_sched_barrier(0);
        __builtin_amdgcn_s_setprio(1);
        MFMA_ROW(0, a0);
        MFMA_ROW(1, a1);
        __builtin_amdgcn_s_setprio(0);
        __builtin_amdgcn_s_barrier();
        __builtin_amdgcn_sched_barrier(0);
        // ---- phase 2 ----
        a0 = *(const bf16x8*)(Ab + (arow + 32) * 32 + rswz);
        a1 = *(const bf16x8*)(Ab + (arow + 48) * 32 + rswz);
        stageB(U + 2);
        __builtin_amdgcn_s_barrier();
        asm volatile("s_waitcnt lgkmcnt(0)" ::: "memory");
        __builtin_amdgcn_sched_barrier(0);
        __builtin_amdgcn_s_setprio(1);
        MFMA_ROW(2, a0);
        MFMA_ROW(3, a1);
        __builtin_amdgcn_s_setprio(0);
        if (U <= NT - 3)      asm volatile("s_waitcnt vmcnt(2)" ::: "memory");
        else if (U == NT - 2) asm volatile("s_waitcnt vmcnt(0)" ::: "memory");
        __builtin_amdgcn_s_barrier();
        __builtin_amdgcn_sched_barrier(0);
    }

#pragma unroll
    for (int r = 0; r < 4; ++r) {
        int v = 512 + m0v + waveA * 64 + r * 16 + quad * 4;
#pragma unroll
        for (int c = 0; c < 4; ++c) {
            int t = n0t + waveB * 64 + c * 16 + l16;
            float4 f;
            f.x = acc[r][c][0]; f.y = acc[r][c][1];
            f.z = acc[r][c][2]; f.w = acc[r][c][3];
            *(float4*)(out + ((size_t)b * SEQ + t) * 1024 + v) = f;
        }
    }
}
#undef MFMA_ROW

extern "C" void kernel_launch(void* const* d_in, const int* in_sizes, int n_in,
                              void* d_out, int out_size, void* d_ws, size_t ws_size,
                              hipStream_t stream) {
    const float* x  = (const float*)d_in[0];
    const float* Wq = (const float*)d_in[1];
    const float* bq = (const float*)d_in[2];
    const float* Wk = (const float*)d_in[3];
    const float* bk = (const float*)d_in[4];
    const float* Wv = (const float*)d_in[5];
    const float* bv = (const float*)d_in[6];
    float* out = (float*)d_out;

    char* ws = (char*)d_ws;
    const size_t QKV_BYTES = (size_t)ROWS * CH * 2;              // 16,777,216
    const size_t E_BYTES   = (size_t)BATCH * SEQ * SEQ * 2;      // 67,108,864
    unsigned short* qkv = (unsigned short*)ws;                   // q,k,v contiguous
    unsigned short* qb = qkv;
    unsigned short* kb = (unsigned short*)(ws + QKV_BYTES);
    unsigned short* vb = (unsigned short*)(ws + 2 * QKV_BYTES);
    unsigned short* E  = (unsigned short*)(ws + 3 * QKV_BYTES);
    float* Z = (float*)(ws + 3 * QKV_BYTES + E_BYTES);
    // Aliases (lifetimes disjoint on the in-order stream):
    unsigned short* xb = E;                                       // dead before logits writes E
    unsigned short* Wt = (unsigned short*)((char*)E + QKV_BYTES); // dead before logits writes E
    unsigned short* Vt = qb;                                      // qb dead after logits

    dim3 blk(256);
    fuse_x_kernel<<<dim3(4096), blk, 0, stream>>>(x, xb, out, Z);
    transpose_w_kernel<<<dim3(8, 8, 3), blk, 0, stream>>>(Wq, Wk, Wv, Wt);
    qkv8_kernel<<<dim3(768), dim3(512), 0, stream>>>(xb, Wt, bq, bk, bv, qkv);
    logits8_kernel<<<dim3(576), dim3(512), 0, stream>>>(qb, kb, E, Z);
    transpose_v_kernel<<<dim3(32, 8, 8), blk, 0, stream>>>(vb, Z, Vt);
    read8_kernel<<<dim3(512), blk, 0, stream>>>(E, Vt, out);
}

// Round 4
// 221.720 us; speedup vs baseline: 1.0592x; 1.0133x over previous
//
#include <hip/hip_runtime.h>
#include <hip/hip_bf16.h>
#include <math.h>

// Problem constants
#define BATCH 8
#define SEQ   2048
#define CH    512
#define ROWS  (BATCH * SEQ)   // 16384
#define INVSQ 0.044194173824159216f  // 1/sqrt(512)

#define BM 128
#define TP 68                  // transpose-tile pitch (2-way conflict = free)

typedef __attribute__((ext_vector_type(8))) __bf16 bf16x8;
typedef __attribute__((ext_vector_type(4))) float f32x4;

__device__ inline unsigned short f2bf(float f) {
    unsigned u = __builtin_bit_cast(unsigned, f);
    u += 0x7fffu + ((u >> 16) & 1u);   // round-to-nearest-even
    return (unsigned short)(u >> 16);
}
__device__ inline float bf2f(unsigned short s) {
    unsigned u = ((unsigned)s) << 16;
    return __builtin_bit_cast(float, u);
}

// ---------------------------------------------------------------------------
// fuse_x: x fp32 [16384,512] -> out[:, :, 0:512] (fp32) AND xb (bf16).
// Also zeroes Z (blocks 0..63).
// ---------------------------------------------------------------------------
__global__ __launch_bounds__(256) void fuse_x_kernel(
    const float* __restrict__ x, unsigned short* __restrict__ xb,
    float* __restrict__ out, float* __restrict__ Z)
{
    if (blockIdx.x < 64) Z[blockIdx.x * 256 + threadIdx.x] = 0.f;
    size_t base = ((size_t)blockIdx.x * 256 + threadIdx.x) * 8;
    size_t row = base >> 9, c = base & 511;
    float4 v0 = *(const float4*)(x + base);
    float4 v1 = *(const float4*)(x + base + 4);
    float* o = out + row * 1024 + c;
    *(float4*)o = v0;
    *(float4*)(o + 4) = v1;
    alignas(16) unsigned short t[8];
    t[0] = f2bf(v0.x); t[1] = f2bf(v0.y); t[2] = f2bf(v0.z); t[3] = f2bf(v0.w);
    t[4] = f2bf(v1.x); t[5] = f2bf(v1.y); t[6] = f2bf(v1.z); t[7] = f2bf(v1.w);
    *(uint4*)(xb + base) = *(const uint4*)t;
}

// ---------------------------------------------------------------------------
// transpose_w: W fp32 [512 k][512 n] -> Wt bf16 [3][512 n][512 k]
// ---------------------------------------------------------------------------
__global__ __launch_bounds__(256) void transpose_w_kernel(
    const float* __restrict__ Wq, const float* __restrict__ Wk,
    const float* __restrict__ Wv, unsigned short* __restrict__ Wt)
{
    __shared__ unsigned short T[64 * TP];
    const int k0 = blockIdx.x * 64, n0 = blockIdx.y * 64, w = blockIdx.z;
    const float* W = (w == 0) ? Wq : (w == 1) ? Wk : Wv;
    const int tid = threadIdx.x;
#pragma unroll
    for (int i = 0; i < 2; ++i) {
        int slot = tid + i * 256;
        int kr = slot >> 3, c8 = (slot & 7) << 3;
        float4 a = *(const float4*)(W + (size_t)(k0 + kr) * CH + n0 + c8);
        float4 b = *(const float4*)(W + (size_t)(k0 + kr) * CH + n0 + c8 + 4);
        T[(c8 + 0) * TP + kr] = f2bf(a.x); T[(c8 + 1) * TP + kr] = f2bf(a.y);
        T[(c8 + 2) * TP + kr] = f2bf(a.z); T[(c8 + 3) * TP + kr] = f2bf(a.w);
        T[(c8 + 4) * TP + kr] = f2bf(b.x); T[(c8 + 5) * TP + kr] = f2bf(b.y);
        T[(c8 + 6) * TP + kr] = f2bf(b.z); T[(c8 + 7) * TP + kr] = f2bf(b.w);
    }
    __syncthreads();
#pragma unroll
    for (int i = 0; i < 2; ++i) {
        int slot = tid + i * 256;
        int nr = slot >> 3, k8 = (slot & 7) << 3;
        uint2 lo = *(const uint2*)(T + nr * TP + k8);
        uint2 hi = *(const uint2*)(T + nr * TP + k8 + 4);
        uint4 u; u.x = lo.x; u.y = lo.y; u.z = hi.x; u.w = hi.y;
        *(uint4*)(Wt + ((size_t)w * CH + n0 + nr) * CH + k0 + k8) = u;
    }
}

// ---------------------------------------------------------------------------
// transpose_v: vb bf16 [b][s][v] -> Vt bf16 [b][v][s], scaled by 1/Z[b][s].
// ---------------------------------------------------------------------------
__global__ __launch_bounds__(256) void transpose_v_kernel(
    const unsigned short* __restrict__ vb, const float* __restrict__ Z,
    unsigned short* __restrict__ Vt)
{
    __shared__ unsigned short T[64 * TP];
    const int s0 = blockIdx.x * 64, v0 = blockIdx.y * 64, b = blockIdx.z;
    const int tid = threadIdx.x;
#pragma unroll
    for (int i = 0; i < 2; ++i) {
        int slot = tid + i * 256;
        int sr = slot >> 3, c8 = (slot & 7) << 3;
        float inv = 1.0f / Z[b * SEQ + s0 + sr];
        uint4 raw = *(const uint4*)(vb + ((size_t)b * SEQ + s0 + sr) * CH + v0 + c8);
        const unsigned short* p = (const unsigned short*)&raw;
#pragma unroll
        for (int j = 0; j < 8; ++j)
            T[(c8 + j) * TP + sr] = f2bf(bf2f(p[j]) * inv);
    }
    __syncthreads();
#pragma unroll
    for (int i = 0; i < 2; ++i) {
        int slot = tid + i * 256;
        int vr = slot >> 3, s8 = (slot & 7) << 3;
        uint2 lo = *(const uint2*)(T + vr * TP + s8);
        uint2 hi = *(const uint2*)(T + vr * TP + s8 + 4);
        uint4 u; u.x = lo.x; u.y = lo.y; u.z = hi.x; u.w = hi.y;
        *(uint4*)(Vt + ((size_t)b * CH + v0 + vr) * SEQ + s0 + s8) = u;
    }
}

// ---------------------------------------------------------------------------
// 2-barrier-per-K-tile counted-vmcnt pipeline (512-thread variant).
// Per tile U: stageA(U+1) early (opposite A-buf, WAR-safe behind U-1's bar2);
// read all 8 frags; lgkmcnt(0) [reads in regs — REQUIRED before bar1];
// bar1; stageB(U+2) [overwrites B(U) slab — safe, all waves' reads done];
// setprio+16 MFMA; vmcnt(2) [in-order retire => B(U+1)ab+A(U+1) complete,
// only B(U+2)ab in flight]; bar2 [cross-wave DMA visibility].
// Tail: vmcnt(0) at U==14 drains for the last tile.
// ---------------------------------------------------------------------------
#define MFMA_ROW(r, af) \
    acc[r][0] = __builtin_amdgcn_mfma_f32_16x16x32_bf16(af, b0, acc[r][0], 0, 0, 0); \
    acc[r][1] = __builtin_amdgcn_mfma_f32_16x16x32_bf16(af, b1, acc[r][1], 0, 0, 0); \
    acc[r][2] = __builtin_amdgcn_mfma_f32_16x16x32_bf16(af, b2, acc[r][2], 0, 0, 0); \
    acc[r][3] = __builtin_amdgcn_mfma_f32_16x16x32_bf16(af, b3, acc[r][3], 0, 0, 0);

#define PIPELINE_LOOP                                                         \
    stageA(0); stageB(0); stageB(1);                                          \
    asm volatile("s_waitcnt vmcnt(2)" ::: "memory");                          \
    __builtin_amdgcn_s_barrier();                                             \
    __builtin_amdgcn_sched_barrier(0);                                        \
    _Pragma("unroll")                                                         \
    for (int U = 0; U < 16; ++U) {                                            \
        const unsigned short* Ab = lds + (U & 1) * 4096;                      \
        const unsigned short* Bb = lds + 8192 + (U & 1) * 8192;               \
        stageA(U + 1);                                                        \
        bf16x8 a0, a1, a2, a3, b0, b1, b2, b3;                                \
        b0 = *(const bf16x8*)(Bb + (brow +  0) * 32 + rswz);                  \
        b1 = *(const bf16x8*)(Bb + (brow + 16) * 32 + rswz);                  \
        b2 = *(const bf16x8*)(Bb + (brow + 32) * 32 + rswz);                  \
        b3 = *(const bf16x8*)(Bb + (brow + 48) * 32 + rswz);                  \
        a0 = *(const bf16x8*)(Ab + (arow +  0) * 32 + rswz);                  \
        a1 = *(const bf16x8*)(Ab + (arow + 16) * 32 + rswz);                  \
        a2 = *(const bf16x8*)(Ab + (arow + 32) * 32 + rswz);                  \
        a3 = *(const bf16x8*)(Ab + (arow + 48) * 32 + rswz);                  \
        asm volatile("s_waitcnt lgkmcnt(0)" ::: "memory");                    \
        __builtin_amdgcn_s_barrier();                                         \
        __builtin_amdgcn_sched_barrier(0);                                    \
        stageB(U + 2);                                                        \
        __builtin_amdgcn_s_setprio(1);                                        \
        MFMA_ROW(0, a0);                                                      \
        MFMA_ROW(1, a1);                                                      \
        MFMA_ROW(2, a2);                                                      \
        MFMA_ROW(3, a3);                                                      \
        __builtin_amdgcn_s_setprio(0);                                        \
        if (U <= 13)      asm volatile("s_waitcnt vmcnt(2)" ::: "memory");    \
        else if (U == 14) asm volatile("s_waitcnt vmcnt(0)" ::: "memory");    \
        __builtin_amdgcn_s_barrier();                                        \
        __builtin_amdgcn_sched_barrier(0);                                    \
    }

// ---------------------------------------------------------------------------
// qkv fused GEMM. C[n(weight row), m(x row)]: A = Wt [1536][512] k-major,
// B = xb [16384][512]. Tile 256(x) x 128(w), BK=32, 16 K-tiles, 8 waves.
// ---------------------------------------------------------------------------
__global__ __launch_bounds__(512, 2) void qkv8_kernel(
    const unsigned short* __restrict__ xb, const unsigned short* __restrict__ Wt,
    const float* __restrict__ bq, const float* __restrict__ bk,
    const float* __restrict__ bv, unsigned short* __restrict__ qkv)
{
    __shared__ unsigned short lds[24576];   // 48 KB
    const int tid = threadIdx.x;
    const int lane = tid & 63, wave = tid >> 6;
    const int waveA = wave >> 2;            // 0..1: weight strip (64 rows)
    const int waveB = wave & 3;             // 0..3: x strip (64 rows)
    const int quad = lane >> 4, l16 = lane & 15;

    // Bijective XCD swizzle: 768 = 8 XCDs x 96. XCD c owns x-tiles 8c..8c+7
    // (= batch c) with all 12 w-tiles -> x-tile staged once per XCD L2.
    int id = (int)blockIdx.x;
    id = (id & 7) * 96 + (id >> 3);
    const int xt = id / 12, wt = id - xt * 12;
    const int xrow0 = xt << 8, wrow0 = wt << 7;

    const unsigned short* __restrict__ Wg = Wt + (size_t)wrow0 * CH;
    const unsigned short* __restrict__ Xg = xb + (size_t)xrow0 * CH;

    // Staging geometry: per-thread source (pre-swizzled slot), linear LDS dest.
    const int srow = tid >> 2;                               // 0..127
    const int scol = (((tid & 3) ^ ((tid >> 3) & 3)) << 3);  // swizzled src col
    const size_t ga  = (size_t)srow * CH + scol;
    const size_t gb1 = (size_t)(srow + 128) * CH + scol;
    const int wdst = wave * 512;                             // ushort idx in slab
    const int rswz = ((quad ^ ((l16 >> 1) & 3)) << 3);       // read-side swizzle
    const int arow = waveA * 64 + l16;
    const int brow = waveB * 64 + l16;

    f32x4 acc[4][4] = {};

    auto stageA = [&](int V) {   // 128x32 weight slab, 1 load/thread
        if (V >= 16) return;
        const unsigned short* g = Wg + ga + V * 32;
        unsigned short* d = lds + (V & 1) * 4096 + wdst;
        __builtin_amdgcn_global_load_lds(
            (const __attribute__((address_space(1))) unsigned int*)g,
            (__attribute__((address_space(3))) unsigned int*)d, 16, 0, 0);
    };
    auto stageB = [&](int V) {   // 256x32 x slab, 2 loads/thread
        if (V >= 16) return;
        const unsigned short* g0 = Xg + ga + V * 32;
        const unsigned short* g1 = Xg + gb1 + V * 32;
        unsigned short* d = lds + 8192 + (V & 1) * 8192 + wdst;
        __builtin_amdgcn_global_load_lds(
            (const __attribute__((address_space(1))) unsigned int*)g0,
            (__attribute__((address_space(3))) unsigned int*)d, 16, 0, 0);
        __builtin_amdgcn_global_load_lds(
            (const __attribute__((address_space(1))) unsigned int*)g1,
            (__attribute__((address_space(3))) unsigned int*)(d + 4096), 16, 0, 0);
    };

    PIPELINE_LOOP

    const int which = wrow0 >> 9;   // uniform per block
    const float* bias = (which == 0) ? bq : (which == 1) ? bk : bv;
    const float scale = (which == 0) ? INVSQ : 1.0f;
    unsigned short* outw = qkv + (size_t)which * ROWS * CH;
    const int colblk = wrow0 & 511;
#pragma unroll
    for (int r = 0; r < 4; ++r) {
        int colb = colblk + waveA * 64 + r * 16 + quad * 4;
        float4 b4 = *(const float4*)(bias + colb);
#pragma unroll
        for (int c = 0; c < 4; ++c) {
            int m = xrow0 + waveB * 64 + c * 16 + l16;
            alignas(8) unsigned short pk[4];
            pk[0] = f2bf((acc[r][c][0] + b4.x) * scale);
            pk[1] = f2bf((acc[r][c][1] + b4.y) * scale);
            pk[2] = f2bf((acc[r][c][2] + b4.z) * scale);
            pk[3] = f2bf((acc[r][c][3] + b4.w) * scale);
            *(uint2*)(outw + (size_t)m * CH + colb) = *(const uint2*)pk;
        }
    }
}

// ---------------------------------------------------------------------------
// logits, pipelined: C[s][t] = k_s . q_t (q pre-scaled by INVSQ).
// A = K-tile [128 s][512 k], B = Q-tile [256 t][512 k]. Same pipeline as qkv8.
// Triangle over (st 128-wide, tt2 256-wide): live iff st <= 2*tt2+1 -> 72
// pairs x 8 batches = 576 blocks. b = blockIdx&7 pins batch b to XCD b.
// E[t][s] = exp(C) if s<=t else 0. Z[s] via shuffle+atomic.
// Coverage: for t-tile tau (128-wide), s-tiles 0..(tau|1) written, superset of
// the 0..tau that read consumes; extras are exact zeros, never read.
// ---------------------------------------------------------------------------
__global__ __launch_bounds__(512, 2) void logits8_kernel(
    const unsigned short* __restrict__ qb, const unsigned short* __restrict__ kb,
    unsigned short* __restrict__ E, float* __restrict__ Z)
{
    __shared__ unsigned short lds[24576];   // 48 KB
    const int tid = threadIdx.x;
    const int lane = tid & 63, wave = tid >> 6;
    const int waveA = wave >> 2;            // 0..1: s strip (64 rows)
    const int waveB = wave & 3;             // 0..3: t strip (64 rows)
    const int quad = lane >> 4, l16 = lane & 15;

    const int b = (int)blockIdx.x & 7;
    const int i = (int)blockIdx.x >> 3;     // 0..71 triangle index
    int tt2 = (int)((sqrtf(4.f * (float)i + 1.f) - 1.f) * 0.5f);
    int st = i - tt2 * (tt2 + 1);
    while (st < 0)           { --tt2; st = i - tt2 * (tt2 + 1); }
    while (st > 2 * tt2 + 1) { ++tt2; st = i - tt2 * (tt2 + 1); }
    const int m0s = st << 7;    // s rows (A, from k), 128-wide
    const int n0t = tt2 << 8;   // t cols (B, from q), 256-wide

    const unsigned short* __restrict__ Wg = kb + ((size_t)b * SEQ + m0s) * CH;
    const unsigned short* __restrict__ Xg = qb + ((size_t)b * SEQ + n0t) * CH;

    const int srow = tid >> 2;
    const int scol = (((tid & 3) ^ ((tid >> 3) & 3)) << 3);
    const size_t ga  = (size_t)srow * CH + scol;
    const size_t gb1 = (size_t)(srow + 128) * CH + scol;
    const int wdst = wave * 512;
    const int rswz = ((quad ^ ((l16 >> 1) & 3)) << 3);
    const int arow = waveA * 64 + l16;
    const int brow = waveB * 64 + l16;

    f32x4 acc[4][4] = {};

    auto stageA = [&](int V) {   // 128x32 K slab
        if (V >= 16) return;
        const unsigned short* g = Wg + ga + V * 32;
        unsigned short* d = lds + (V & 1) * 4096 + wdst;
        __builtin_amdgcn_global_load_lds(
            (const __attribute__((address_space(1))) unsigned int*)g,
            (__attribute__((address_space(3))) unsigned int*)d, 16, 0, 0);
    };
    auto stageB = [&](int V) {   // 256x32 Q slab
        if (V >= 16) return;
        const unsigned short* g0 = Xg + ga + V * 32;
        const unsigned short* g1 = Xg + gb1 + V * 32;
        unsigned short* d = lds + 8192 + (V & 1) * 8192 + wdst;
        __builtin_amdgcn_global_load_lds(
            (const __attribute__((address_space(1))) unsigned int*)g0,
            (__attribute__((address_space(3))) unsigned int*)d, 16, 0, 0);
        __builtin_amdgcn_global_load_lds(
            (const __attribute__((address_space(1))) unsigned int*)g1,
            (__attribute__((address_space(3))) unsigned int*)(d + 4096), 16, 0, 0);
    };

    PIPELINE_LOOP

    // Epilogue: causal mask, exp, Z partial sums, bf16 E write.
#pragma unroll
    for (int r = 0; r < 4; ++r) {
        int sb = m0s + waveA * 64 + r * 16 + quad * 4;
        float ev[4][4];
#pragma unroll
        for (int c = 0; c < 4; ++c) {
            int t = n0t + waveB * 64 + c * 16 + l16;
#pragma unroll
            for (int reg = 0; reg < 4; ++reg)
                ev[c][reg] = (sb + reg <= t) ? __expf(acc[r][c][reg]) : 0.f;
        }
#pragma unroll
        for (int reg = 0; reg < 4; ++reg) {
            float z = ev[0][reg] + ev[1][reg] + ev[2][reg] + ev[3][reg];
            z += __shfl_xor(z, 1);
            z += __shfl_xor(z, 2);
            z += __shfl_xor(z, 4);
            z += __shfl_xor(z, 8);
            if (l16 == 0) atomicAdd(&Z[b * SEQ + sb + reg], z);
        }
#pragma unroll
        for (int c = 0; c < 4; ++c) {
            int t = n0t + waveB * 64 + c * 16 + l16;
            alignas(8) unsigned short pk[4];
            pk[0] = f2bf(ev[c][0]); pk[1] = f2bf(ev[c][1]);
            pk[2] = f2bf(ev[c][2]); pk[3] = f2bf(ev[c][3]);
            *(uint2*)(E + ((size_t)b * SEQ + t) * SEQ + sb) = *(const uint2*)pk;
        }
    }
}
#undef PIPELINE_LOOP

// ---------------------------------------------------------------------------
// read, pipelined 256-thread variant: C[v][t] = sum_s Vt[v][s] * E[t][s].
// A = Vt tile [128 v][s], B = E tile [128 t][s], both stride SEQ. BK=32,
// runtime NT = 4*(tt+1) K-tiles (causal). 4 waves (2 over v, 2 over t).
// LDS 32 KB: A[2][128][32] | B[2][128][32]. Same 2-barrier/tile pipeline.
// ---------------------------------------------------------------------------
__global__ __launch_bounds__(256, 2) void read8_kernel(
    const unsigned short* __restrict__ E, const unsigned short* __restrict__ Vt,
    float* __restrict__ out)
{
    __shared__ unsigned short lds[16384];   // 32 KB
    const int tid = threadIdx.x;
    const int lane = tid & 63, wave = tid >> 6;
    const int waveA = wave >> 1;            // 0..1: v strip (64 rows)
    const int waveB = wave & 1;             // 0..1: t strip (64 rows)
    const int quad = lane >> 4, l16 = lane & 15;

    const int id = blockIdx.x;
    const int b = id & 7;
    const int rem = id >> 3;
    const int mv = rem & 3;                  // v tile (4)
    const int r0 = rem >> 2;                 // 0..15
    const int tt = (r0 < 8) ? r0 : 23 - r0;  // paired so per-CU work balances
    const int m0v = mv * BM;
    const int n0t = tt * BM;
    const int NT = (tt + 1) * 4;             // K-tiles of 32 (causal extent)

    const unsigned short* __restrict__ Ag = Vt + ((size_t)b * CH + m0v) * SEQ;
    const unsigned short* __restrict__ Bg = E + ((size_t)b * SEQ + n0t) * SEQ;

    // Staging: lane-linear LDS dest; source col slot pre-swizzled.
    const int scol = (((lane & 3) ^ ((lane >> 3) & 3)) << 3);
    const int srow = wave * 16 + (lane >> 2);       // 0..63 within half-slab
    const size_t ga0 = (size_t)srow * SEQ + scol;
    const size_t ga1 = (size_t)(srow + 64) * SEQ + scol;
    const int wdst = wave * 512;
    const int rswz = ((quad ^ ((l16 >> 1) & 3)) << 3);
    const int arow = waveA * 64 + l16;
    const int brow = waveB * 64 + l16;

    f32x4 acc[4][4] = {};

    auto stageA = [&](int V) {   // 128x32 Vt slab, 2 loads/thread
        if (V >= NT) return;
        const unsigned short* g0 = Ag + ga0 + V * 32;
        const unsigned short* g1 = Ag + ga1 + V * 32;
        unsigned short* d = lds + (V & 1) * 4096 + wdst;
        __builtin_amdgcn_global_load_lds(
            (const __attribute__((address_space(1))) unsigned int*)g0,
            (__attribute__((address_space(3))) unsigned int*)d, 16, 0, 0);
        __builtin_amdgcn_global_load_lds(
            (const __attribute__((address_space(1))) unsigned int*)g1,
            (__attribute__((address_space(3))) unsigned int*)(d + 2048), 16, 0, 0);
    };
    auto stageB = [&](int V) {   // 128x32 E slab, 2 loads/thread
        if (V >= NT) return;
        const unsigned short* g0 = Bg + ga0 + V * 32;
        const unsigned short* g1 = Bg + ga1 + V * 32;
        unsigned short* d = lds + 8192 + (V & 1) * 4096 + wdst;
        __builtin_amdgcn_global_load_lds(
            (const __attribute__((address_space(1))) unsigned int*)g0,
            (__attribute__((address_space(3))) unsigned int*)d, 16, 0, 0);
        __builtin_amdgcn_global_load_lds(
            (const __attribute__((address_space(1))) unsigned int*)g1,
            (__attribute__((address_space(3))) unsigned int*)(d + 2048), 16, 0, 0);
    };

    stageA(0); stageB(0); stageB(1);
    asm volatile("s_waitcnt vmcnt(2)" ::: "memory");
    __builtin_amdgcn_s_barrier();
    __builtin_amdgcn_sched_barrier(0);

#pragma unroll 2
    for (int U = 0; U < NT; ++U) {
        const unsigned short* Ab = lds + (U & 1) * 4096;
        const unsigned short* Bb = lds + 8192 + (U & 1) * 4096;
        stageA(U + 1);
        bf16x8 a0, a1, a2, a3, b0, b1, b2, b3;
        b0 = *(const bf16x8*)(Bb + (brow +  0) * 32 + rswz);
        b1 = *(const bf16x8*)(Bb + (brow + 16) * 32 + rswz);
        b2 = *(const bf16x8*)(Bb + (brow + 32) * 32 + rswz);
        b3 = *(const bf16x8*)(Bb + (brow + 48) * 32 + rswz);
        a0 = *(const bf16x8*)(Ab + (arow +  0) * 32 + rswz);
        a1 = *(const bf16x8*)(Ab + (arow + 16) * 32 + rswz);
        a2 = *(const bf16x8*)(Ab + (arow + 32) * 32 + rswz);
        a3 = *(const bf16x8*)(Ab + (arow + 48) * 32 + rswz);
        asm volatile("s_waitcnt lgkmcnt(0)" ::: "memory");
        __builtin_amdgcn_s_barrier();
        __builtin_amdgcn_sched_barrier(0);
        stageB(U + 2);
        __builtin_amdgcn_s_setprio(1);
        MFMA_ROW(0, a0);
        MFMA_ROW(1, a1);
        MFMA_ROW(2, a2);
        MFMA_ROW(3, a3);
        __builtin_amdgcn_s_setprio(0);
        if (U <= NT - 3)      asm volatile("s_waitcnt vmcnt(2)" ::: "memory");
        else if (U == NT - 2) asm volatile("s_waitcnt vmcnt(0)" ::: "memory");
        __builtin_amdgcn_s_barrier();
        __builtin_amdgcn_sched_barrier(0);
    }

#pragma unroll
    for (int r = 0; r < 4; ++r) {
        int v = 512 + m0v + waveA * 64 + r * 16 + quad * 4;
#pragma unroll
        for (int c = 0; c < 4; ++c) {
            int t = n0t + waveB * 64 + c * 16 + l16;
            float4 f;
            f.x = acc[r][c][0]; f.y = acc[r][c][1];
            f.z = acc[r][c][2]; f.w = acc[r][c][3];
            *(float4*)(out + ((size_t)b * SEQ + t) * 1024 + v) = f;
        }
    }
}
#undef MFMA_ROW

extern "C" void kernel_launch(void* const* d_in, const int* in_sizes, int n_in,
                              void* d_out, int out_size, void* d_ws, size_t ws_size,
                              hipStream_t stream) {
    const float* x  = (const float*)d_in[0];
    const float* Wq = (const float*)d_in[1];
    const float* bq = (const float*)d_in[2];
    const float* Wk = (const float*)d_in[3];
    const float* bk = (const float*)d_in[4];
    const float* Wv = (const float*)d_in[5];
    const float* bv = (const float*)d_in[6];
    float* out = (float*)d_out;

    char* ws = (char*)d_ws;
    const size_t QKV_BYTES = (size_t)ROWS * CH * 2;              // 16,777,216
    const size_t E_BYTES   = (size_t)BATCH * SEQ * SEQ * 2;      // 67,108,864
    unsigned short* qkv = (unsigned short*)ws;                   // q,k,v contiguous
    unsigned short* qb = qkv;
    unsigned short* kb = (unsigned short*)(ws + QKV_BYTES);
    unsigned short* vb = (unsigned short*)(ws + 2 * QKV_BYTES);
    unsigned short* E  = (unsigned short*)(ws + 3 * QKV_BYTES);
    float* Z = (float*)(ws + 3 * QKV_BYTES + E_BYTES);
    // Aliases (lifetimes disjoint on the in-order stream):
    unsigned short* xb = E;                                       // dead before logits writes E
    unsigned short* Wt = (unsigned short*)((char*)E + QKV_BYTES); // dead before logits writes E
    unsigned short* Vt = qb;                                      // qb dead after logits

    dim3 blk(256);
    fuse_x_kernel<<<dim3(4096), blk, 0, stream>>>(x, xb, out, Z);
    transpose_w_kernel<<<dim3(8, 8, 3), blk, 0, stream>>>(Wq, Wk, Wv, Wt);
    qkv8_kernel<<<dim3(768), dim3(512), 0, stream>>>(xb, Wt, bq, bk, bv, qkv);
    logits8_kernel<<<dim3(576), dim3(512), 0, stream>>>(qb, kb, E, Z);
    transpose_v_kernel<<<dim3(32, 8, 8), blk, 0, stream>>>(vb, Z, Vt);
    read8_kernel<<<dim3(512), blk, 0, stream>>>(E, Vt, out);
}

// Round 5
// 213.931 us; speedup vs baseline: 1.0978x; 1.0364x over previous
//
#include <hip/hip_runtime.h>
#include <hip/hip_bf16.h>
#include <math.h>

// Problem constants
#define BATCH 8
#define SEQ   2048
#define CH    512
#define ROWS  (BATCH * SEQ)   // 16384
#define INVSQ 0.044194173824159216f  // 1/sqrt(512)

#define TP 68                  // transpose-tile pitch (2-way conflict = free)

typedef __attribute__((ext_vector_type(8))) __bf16 bf16x8;
typedef __attribute__((ext_vector_type(4))) float f32x4;

__device__ inline unsigned short f2bf(float f) {
    unsigned u = __builtin_bit_cast(unsigned, f);
    u += 0x7fffu + ((u >> 16) & 1u);   // round-to-nearest-even
    return (unsigned short)(u >> 16);
}
__device__ inline float bf2f(unsigned short s) {
    unsigned u = ((unsigned)s) << 16;
    return __builtin_bit_cast(float, u);
}

// ---------------------------------------------------------------------------
// fuse_x: x fp32 [16384,512] -> out[:, :, 0:512] (fp32) AND xb (bf16).
// Also zeroes Z (blocks 0..63).
// ---------------------------------------------------------------------------
__global__ __launch_bounds__(256) void fuse_x_kernel(
    const float* __restrict__ x, unsigned short* __restrict__ xb,
    float* __restrict__ out, float* __restrict__ Z)
{
    if (blockIdx.x < 64) Z[blockIdx.x * 256 + threadIdx.x] = 0.f;
    size_t base = ((size_t)blockIdx.x * 256 + threadIdx.x) * 8;
    size_t row = base >> 9, c = base & 511;
    float4 v0 = *(const float4*)(x + base);
    float4 v1 = *(const float4*)(x + base + 4);
    float* o = out + row * 1024 + c;
    *(float4*)o = v0;
    *(float4*)(o + 4) = v1;
    alignas(16) unsigned short t[8];
    t[0] = f2bf(v0.x); t[1] = f2bf(v0.y); t[2] = f2bf(v0.z); t[3] = f2bf(v0.w);
    t[4] = f2bf(v1.x); t[5] = f2bf(v1.y); t[6] = f2bf(v1.z); t[7] = f2bf(v1.w);
    *(uint4*)(xb + base) = *(const uint4*)t;
}

// ---------------------------------------------------------------------------
// transpose_w: W fp32 [512 k][512 n] -> Wt bf16 [3][512 n][512 k]
// ---------------------------------------------------------------------------
__global__ __launch_bounds__(256) void transpose_w_kernel(
    const float* __restrict__ Wq, const float* __restrict__ Wk,
    const float* __restrict__ Wv, unsigned short* __restrict__ Wt)
{
    __shared__ unsigned short T[64 * TP];
    const int k0 = blockIdx.x * 64, n0 = blockIdx.y * 64, w = blockIdx.z;
    const float* W = (w == 0) ? Wq : (w == 1) ? Wk : Wv;
    const int tid = threadIdx.x;
#pragma unroll
    for (int i = 0; i < 2; ++i) {
        int slot = tid + i * 256;
        int kr = slot >> 3, c8 = (slot & 7) << 3;
        float4 a = *(const float4*)(W + (size_t)(k0 + kr) * CH + n0 + c8);
        float4 b = *(const float4*)(W + (size_t)(k0 + kr) * CH + n0 + c8 + 4);
        T[(c8 + 0) * TP + kr] = f2bf(a.x); T[(c8 + 1) * TP + kr] = f2bf(a.y);
        T[(c8 + 2) * TP + kr] = f2bf(a.z); T[(c8 + 3) * TP + kr] = f2bf(a.w);
        T[(c8 + 4) * TP + kr] = f2bf(b.x); T[(c8 + 5) * TP + kr] = f2bf(b.y);
        T[(c8 + 6) * TP + kr] = f2bf(b.z); T[(c8 + 7) * TP + kr] = f2bf(b.w);
    }
    __syncthreads();
#pragma unroll
    for (int i = 0; i < 2; ++i) {
        int slot = tid + i * 256;
        int nr = slot >> 3, k8 = (slot & 7) << 3;
        uint2 lo = *(const uint2*)(T + nr * TP + k8);
        uint2 hi = *(const uint2*)(T + nr * TP + k8 + 4);
        uint4 u; u.x = lo.x; u.y = lo.y; u.z = hi.x; u.w = hi.y;
        *(uint4*)(Wt + ((size_t)w * CH + n0 + nr) * CH + k0 + k8) = u;
    }
}

// ---------------------------------------------------------------------------
// transpose_v: vb bf16 [b][s][v] -> Vt bf16 [b][v][s], scaled by 1/Z[b][s].
// ---------------------------------------------------------------------------
__global__ __launch_bounds__(256) void transpose_v_kernel(
    const unsigned short* __restrict__ vb, const float* __restrict__ Z,
    unsigned short* __restrict__ Vt)
{
    __shared__ unsigned short T[64 * TP];
    const int s0 = blockIdx.x * 64, v0 = blockIdx.y * 64, b = blockIdx.z;
    const int tid = threadIdx.x;
#pragma unroll
    for (int i = 0; i < 2; ++i) {
        int slot = tid + i * 256;
        int sr = slot >> 3, c8 = (slot & 7) << 3;
        float inv = 1.0f / Z[b * SEQ + s0 + sr];
        uint4 raw = *(const uint4*)(vb + ((size_t)b * SEQ + s0 + sr) * CH + v0 + c8);
        const unsigned short* p = (const unsigned short*)&raw;
#pragma unroll
        for (int j = 0; j < 8; ++j)
            T[(c8 + j) * TP + sr] = f2bf(bf2f(p[j]) * inv);
    }
    __syncthreads();
#pragma unroll
    for (int i = 0; i < 2; ++i) {
        int slot = tid + i * 256;
        int vr = slot >> 3, s8 = (slot & 7) << 3;
        uint2 lo = *(const uint2*)(T + vr * TP + s8);
        uint2 hi = *(const uint2*)(T + vr * TP + s8 + 4);
        uint4 u; u.x = lo.x; u.y = lo.y; u.z = hi.x; u.w = hi.y;
        *(uint4*)(Vt + ((size_t)b * CH + v0 + vr) * SEQ + s0 + s8) = u;
    }
}

// ---------------------------------------------------------------------------
// 128x128-tile BK=64 2-barrier counted-vmcnt pipeline, 256 thr / 4 waves.
// LDS 64 KB: A[2][128][64] | B[2][128][64] bf16, 128-B rows.
// Swizzle (both sides, involution chunk^=(row&7) on 16-B slots):
//   stage: linear LDS dest (tid*16B within slab), global source col
//          pre-swizzled -> LDS[row][chunk] holds global chunk (chunk^row&7).
//   read:  frag (h,quad) reads LDS slot (h*4+quad)^(row&7) -> global chunk ok.
//   16 lanes/quarter -> 8 slots x 2 rows = 2-way bank alias = free.
// Per tile U: stageA(U+1) [WAR-safe: that slab's reads retired at U-1's bar1];
// read 16 frags; lgkmcnt(0); bar1; stageB(U+2) [overwrites B(U), reads done];
// 32 MFMA; vmcnt(4) [in-order retire => A(U+1),B(U+1) landed, only B(U+2)'s
// 4 loads in flight]; bar2. Tail: vmcnt(0) at U==NT-2.
// ---------------------------------------------------------------------------
#define FRAG_READS                                                            \
    bf16x8 a0[4], a1[4], c0[4], c1[4];                                        \
    _Pragma("unroll")                                                         \
    for (int rr = 0; rr < 4; ++rr) {                                          \
        const unsigned short* ap = Ab + (arow + rr * 16) * 64;                \
        const unsigned short* bp = Bb + (brow + rr * 16) * 64;                \
        a0[rr] = *(const bf16x8*)(ap + s80);                                  \
        a1[rr] = *(const bf16x8*)(ap + s81);                                  \
        c0[rr] = *(const bf16x8*)(bp + s80);                                  \
        c1[rr] = *(const bf16x8*)(bp + s81);                                  \
    }

#define MFMA_TILE                                                             \
    _Pragma("unroll")                                                         \
    for (int rr = 0; rr < 4; ++rr)                                            \
        _Pragma("unroll")                                                     \
        for (int cc = 0; cc < 4; ++cc)                                        \
            acc[rr][cc] = __builtin_amdgcn_mfma_f32_16x16x32_bf16(            \
                a0[rr], c0[cc], acc[rr][cc], 0, 0, 0);                        \
    _Pragma("unroll")                                                         \
    for (int rr = 0; rr < 4; ++rr)                                            \
        _Pragma("unroll")                                                     \
        for (int cc = 0; cc < 4; ++cc)                                        \
            acc[rr][cc] = __builtin_amdgcn_mfma_f32_16x16x32_bf16(            \
                a1[rr], c1[cc], acc[rr][cc], 0, 0, 0);

#define STAGE4(gsrc, dslab)                                                   \
    _Pragma("unroll")                                                         \
    for (int p = 0; p < 4; ++p)                                               \
        __builtin_amdgcn_global_load_lds(                                     \
            (const __attribute__((address_space(1))) unsigned int*)((gsrc) + (size_t)p * 32 * gstride), \
            (__attribute__((address_space(3))) unsigned int*)((dslab) + p * 2048 + (tid << 3)), \
            16, 0, 0);

#define PIPE_PROLOGUE                                                         \
    stageA(0); stageB(0); stageB(1);                                          \
    asm volatile("s_waitcnt vmcnt(4)" ::: "memory");                          \
    __builtin_amdgcn_s_barrier();                                             \
    __builtin_amdgcn_sched_barrier(0);

#define PIPE_BODY(NTv)                                                        \
    {                                                                         \
        const unsigned short* Ab = lds + (U & 1) * 8192;                      \
        const unsigned short* Bb = lds + 16384 + (U & 1) * 8192;              \
        stageA(U + 1);                                                        \
        FRAG_READS                                                            \
        asm volatile("s_waitcnt lgkmcnt(0)" ::: "memory");                    \
        __builtin_amdgcn_s_barrier();                                         \
        __builtin_amdgcn_sched_barrier(0);                                    \
        stageB(U + 2);                                                        \
        __builtin_amdgcn_s_setprio(1);                                        \
        MFMA_TILE                                                             \
        __builtin_amdgcn_s_setprio(0);                                        \
        if (U <= (NTv) - 3)      asm volatile("s_waitcnt vmcnt(4)" ::: "memory"); \
        else if (U == (NTv) - 2) asm volatile("s_waitcnt vmcnt(0)" ::: "memory"); \
        __builtin_amdgcn_s_barrier();                                         \
        __builtin_amdgcn_sched_barrier(0);                                    \
    }

// ---------------------------------------------------------------------------
// qkv fused GEMM. C[wr(weight row), m(x row)]: A = Wt [1536][512] k-major,
// B = xb [16384][512]. Tile 128(w) x 128(x), BK=64, 8 K-tiles.
// Grid 1536 = 128 xt x 12 wt; bijective XCD swizzle (1536 = 8 x 192).
// ---------------------------------------------------------------------------
__global__ __launch_bounds__(256, 2) void qkv8_kernel(
    const unsigned short* __restrict__ xb, const unsigned short* __restrict__ Wt,
    const float* __restrict__ bq, const float* __restrict__ bk,
    const float* __restrict__ bv, unsigned short* __restrict__ qkv)
{
    __shared__ unsigned short lds[32768];   // 64 KB
    const int tid = threadIdx.x;
    const int lane = tid & 63, wave = tid >> 6;
    const int waveA = wave >> 1;            // 0..1: weight strip (64 rows)
    const int waveB = wave & 1;             // 0..1: x strip (64 rows)
    const int quad = lane >> 4, l16 = lane & 15;

    int id = (int)blockIdx.x;
    id = (id & 7) * 192 + (id >> 3);        // XCD c owns x-tiles 16c..16c+15
    const int xt = id / 12, wt = id - xt * 12;
    const int xrow0 = xt << 7, wrow0 = wt << 7;

    const size_t gstride = CH;
    const unsigned short* __restrict__ Wg = Wt + (size_t)wrow0 * CH;
    const unsigned short* __restrict__ Xg = xb + (size_t)xrow0 * CH;

    // Staging: rows tid>>3 (+32 per pass), source chunk pre-swizzled.
    const int scol = (((tid & 7) ^ ((tid >> 3) & 7)) << 3);
    const size_t ga = (size_t)(tid >> 3) * gstride + scol;
    // Read-side swizzle: slot (h*4+quad)^(row&7), row&7 == l16&7.
    const int s80 = ((quad ^ (l16 & 7)) << 3);
    const int s81 = s80 ^ 32;
    const int arow = waveA * 64 + l16;
    const int brow = waveB * 64 + l16;

    f32x4 acc[4][4] = {};

    auto stageA = [&](int V) {
        if (V >= 8) return;
        const unsigned short* g = Wg + ga + V * 64;
        unsigned short* d = lds + (V & 1) * 8192;
        STAGE4(g, d)
    };
    auto stageB = [&](int V) {
        if (V >= 8) return;
        const unsigned short* g = Xg + ga + V * 64;
        unsigned short* d = lds + 16384 + (V & 1) * 8192;
        STAGE4(g, d)
    };

    PIPE_PROLOGUE
#pragma unroll
    for (int U = 0; U < 8; ++U) PIPE_BODY(8)

    const int which = wrow0 >> 9;   // uniform per block
    const float* bias = (which == 0) ? bq : (which == 1) ? bk : bv;
    const float scale = (which == 0) ? INVSQ : 1.0f;
    unsigned short* outw = qkv + (size_t)which * ROWS * CH;
    const int colblk = wrow0 & 511;
#pragma unroll
    for (int r = 0; r < 4; ++r) {
        int colb = colblk + waveA * 64 + r * 16 + quad * 4;
        float4 b4 = *(const float4*)(bias + colb);
#pragma unroll
        for (int c = 0; c < 4; ++c) {
            int m = xrow0 + waveB * 64 + c * 16 + l16;
            alignas(8) unsigned short pk[4];
            pk[0] = f2bf((acc[r][c][0] + b4.x) * scale);
            pk[1] = f2bf((acc[r][c][1] + b4.y) * scale);
            pk[2] = f2bf((acc[r][c][2] + b4.z) * scale);
            pk[3] = f2bf((acc[r][c][3] + b4.w) * scale);
            *(uint2*)(outw + (size_t)m * CH + colb) = *(const uint2*)pk;
        }
    }
}

// ---------------------------------------------------------------------------
// logits: C[s][t] = k_s . q_t (q pre-scaled). A = K-tile [128 s][512 k],
// B = Q-tile [128 t][512 k]. Triangle st<=tt: 136 pairs x 8 b = 1088 blocks
// (4.25/CU -> small tail). b = blockIdx&7 pins batch to XCD.
// E[t][s] = exp(C) if s<=t else 0; Z[s] via shuffle+atomic.
// ---------------------------------------------------------------------------
__global__ __launch_bounds__(256, 2) void logits8_kernel(
    const unsigned short* __restrict__ qb, const unsigned short* __restrict__ kb,
    unsigned short* __restrict__ E, float* __restrict__ Z)
{
    __shared__ unsigned short lds[32768];   // 64 KB
    const int tid = threadIdx.x;
    const int lane = tid & 63, wave = tid >> 6;
    const int waveA = wave >> 1;            // 0..1: s strip
    const int waveB = wave & 1;             // 0..1: t strip
    const int quad = lane >> 4, l16 = lane & 15;

    const int b = (int)blockIdx.x & 7;
    const int i = (int)blockIdx.x >> 3;     // 0..135 triangle index
    int tt = (int)((sqrtf(8.f * (float)i + 1.f) - 1.f) * 0.5f);
    int st = i - ((tt * (tt + 1)) >> 1);
    while (st < 0)  { --tt; st = i - ((tt * (tt + 1)) >> 1); }
    while (st > tt) { ++tt; st = i - ((tt * (tt + 1)) >> 1); }
    const int m0s = st << 7;    // s rows (A, from k)
    const int n0t = tt << 7;    // t rows (B, from q)

    const size_t gstride = CH;
    const unsigned short* __restrict__ Ag = kb + ((size_t)b * SEQ + m0s) * CH;
    const unsigned short* __restrict__ Bg = qb + ((size_t)b * SEQ + n0t) * CH;

    const int scol = (((tid & 7) ^ ((tid >> 3) & 7)) << 3);
    const size_t ga = (size_t)(tid >> 3) * gstride + scol;
    const int s80 = ((quad ^ (l16 & 7)) << 3);
    const int s81 = s80 ^ 32;
    const int arow = waveA * 64 + l16;
    const int brow = waveB * 64 + l16;

    f32x4 acc[4][4] = {};

    auto stageA = [&](int V) {
        if (V >= 8) return;
        const unsigned short* g = Ag + ga + V * 64;
        unsigned short* d = lds + (V & 1) * 8192;
        STAGE4(g, d)
    };
    auto stageB = [&](int V) {
        if (V >= 8) return;
        const unsigned short* g = Bg + ga + V * 64;
        unsigned short* d = lds + 16384 + (V & 1) * 8192;
        STAGE4(g, d)
    };

    PIPE_PROLOGUE
#pragma unroll
    for (int U = 0; U < 8; ++U) PIPE_BODY(8)

    // Epilogue: causal mask, exp, Z partial sums, bf16 E write.
#pragma unroll
    for (int r = 0; r < 4; ++r) {
        int sb = m0s + waveA * 64 + r * 16 + quad * 4;
        float ev[4][4];
#pragma unroll
        for (int c = 0; c < 4; ++c) {
            int t = n0t + waveB * 64 + c * 16 + l16;
#pragma unroll
            for (int reg = 0; reg < 4; ++reg)
                ev[c][reg] = (sb + reg <= t) ? __expf(acc[r][c][reg]) : 0.f;
        }
#pragma unroll
        for (int reg = 0; reg < 4; ++reg) {
            float z = ev[0][reg] + ev[1][reg] + ev[2][reg] + ev[3][reg];
            z += __shfl_xor(z, 1);
            z += __shfl_xor(z, 2);
            z += __shfl_xor(z, 4);
            z += __shfl_xor(z, 8);
            if (l16 == 0) atomicAdd(&Z[b * SEQ + sb + reg], z);
        }
#pragma unroll
        for (int c = 0; c < 4; ++c) {
            int t = n0t + waveB * 64 + c * 16 + l16;
            alignas(8) unsigned short pk[4];
            pk[0] = f2bf(ev[c][0]); pk[1] = f2bf(ev[c][1]);
            pk[2] = f2bf(ev[c][2]); pk[3] = f2bf(ev[c][3]);
            *(uint2*)(E + ((size_t)b * SEQ + t) * SEQ + sb) = *(const uint2*)pk;
        }
    }
}

// ---------------------------------------------------------------------------
// read: C[v][t] = sum_s Vt[v][s] * E[t][s]. A = Vt tile [128 v][s],
// B = E tile [128 t][s], both stride SEQ. BK=64, runtime NT = 2*(tt+1).
// Grid 512 (4v x 16tt-balanced x 8b), b = blockIdx&7 pins XCD.
// ---------------------------------------------------------------------------
__global__ __launch_bounds__(256, 2) void read8_kernel(
    const unsigned short* __restrict__ E, const unsigned short* __restrict__ Vt,
    float* __restrict__ out)
{
    __shared__ unsigned short lds[32768];   // 64 KB
    const int tid = threadIdx.x;
    const int lane = tid & 63, wave = tid >> 6;
    const int waveA = wave >> 1;            // 0..1: v strip
    const int waveB = wave & 1;             // 0..1: t strip
    const int quad = lane >> 4, l16 = lane & 15;

    const int id = blockIdx.x;
    const int b = id & 7;
    const int rem = id >> 3;
    const int mv = rem & 3;                  // v tile (4)
    const int r0 = rem >> 2;                 // 0..15
    const int tt = (r0 < 8) ? r0 : 23 - r0;  // paired so per-CU work balances
    const int m0v = mv << 7;
    const int n0t = tt << 7;
    const int NT = (tt + 1) * 2;             // K-tiles of 64 (causal extent)

    const size_t gstride = SEQ;
    const unsigned short* __restrict__ Ag = Vt + ((size_t)b * CH + m0v) * SEQ;
    const unsigned short* __restrict__ Bg = E + ((size_t)b * SEQ + n0t) * SEQ;

    const int scol = (((tid & 7) ^ ((tid >> 3) & 7)) << 3);
    const size_t ga = (size_t)(tid >> 3) * gstride + scol;
    const int s80 = ((quad ^ (l16 & 7)) << 3);
    const int s81 = s80 ^ 32;
    const int arow = waveA * 64 + l16;
    const int brow = waveB * 64 + l16;

    f32x4 acc[4][4] = {};

    auto stageA = [&](int V) {
        if (V >= NT) return;
        const unsigned short* g = Ag + ga + V * 64;
        unsigned short* d = lds + (V & 1) * 8192;
        STAGE4(g, d)
    };
    auto stageB = [&](int V) {
        if (V >= NT) return;
        const unsigned short* g = Bg + ga + V * 64;
        unsigned short* d = lds + 16384 + (V & 1) * 8192;
        STAGE4(g, d)
    };

    PIPE_PROLOGUE
#pragma unroll 2
    for (int U = 0; U < NT; ++U) PIPE_BODY(NT)

#pragma unroll
    for (int r = 0; r < 4; ++r) {
        int v = 512 + m0v + waveA * 64 + r * 16 + quad * 4;
#pragma unroll
        for (int c = 0; c < 4; ++c) {
            int t = n0t + waveB * 64 + c * 16 + l16;
            float4 f;
            f.x = acc[r][c][0]; f.y = acc[r][c][1];
            f.z = acc[r][c][2]; f.w = acc[r][c][3];
            *(float4*)(out + ((size_t)b * SEQ + t) * 1024 + v) = f;
        }
    }
}

extern "C" void kernel_launch(void* const* d_in, const int* in_sizes, int n_in,
                              void* d_out, int out_size, void* d_ws, size_t ws_size,
                              hipStream_t stream) {
    const float* x  = (const float*)d_in[0];
    const float* Wq = (const float*)d_in[1];
    const float* bq = (const float*)d_in[2];
    const float* Wk = (const float*)d_in[3];
    const float* bk = (const float*)d_in[4];
    const float* Wv = (const float*)d_in[5];
    const float* bv = (const float*)d_in[6];
    float* out = (float*)d_out;

    char* ws = (char*)d_ws;
    const size_t QKV_BYTES = (size_t)ROWS * CH * 2;              // 16,777,216
    const size_t E_BYTES   = (size_t)BATCH * SEQ * SEQ * 2;      // 67,108,864
    unsigned short* qkv = (unsigned short*)ws;                   // q,k,v contiguous
    unsigned short* qb = qkv;
    unsigned short* kb = (unsigned short*)(ws + QKV_BYTES);
    unsigned short* vb = (unsigned short*)(ws + 2 * QKV_BYTES);
    unsigned short* E  = (unsigned short*)(ws + 3 * QKV_BYTES);
    float* Z = (float*)(ws + 3 * QKV_BYTES + E_BYTES);
    // Aliases (lifetimes disjoint on the in-order stream):
    unsigned short* xb = E;                                       // dead before logits writes E
    unsigned short* Wt = (unsigned short*)((char*)E + QKV_BYTES); // dead before logits writes E
    unsigned short* Vt = qb;                                      // qb dead after logits

    dim3 blk(256);
    fuse_x_kernel<<<dim3(4096), blk, 0, stream>>>(x, xb, out, Z);
    transpose_w_kernel<<<dim3(8, 8, 3), blk, 0, stream>>>(Wq, Wk, Wv, Wt);
    qkv8_kernel<<<dim3(1536), blk, 0, stream>>>(xb, Wt, bq, bk, bv, qkv);
    logits8_kernel<<<dim3(1088), blk, 0, stream>>>(qb, kb, E, Z);
    transpose_v_kernel<<<dim3(32, 8, 8), blk, 0, stream>>>(vb, Z, Vt);
    read8_kernel<<<dim3(512), blk, 0, stream>>>(E, Vt, out);
}